// Round 2
// baseline (224.258 us; speedup 1.0000x reference)
//
#include <hip/hip_runtime.h>
#include <math.h>

#define BB 2
#define LL 4096
#define HH 8
#define DD 64
#define UU 45
#define TILE 128
#define NTILES (LL / TILE) // 32

// split-K attention config
#define NC 64              // key chunks
#define CK (LL / NC)       // 64 keys per chunk
#define KSTR 68            // padded LDS row stride (floats) for K/V/Q tiles
#define SSTR 68            // padded LDS row stride for scores (CK=64 + 4)

__device__ __forceinline__ int qkv_idx(int b, int l, int h, int d) {
    return ((b * LL + l) * HH + h) * DD + d;
}

// ---------------- Kernel 1: sparsity metric M[b,h,q] ---------------------------
// One wave per query. Lane layout: 4 lanes cooperate per sampled K row
// (quad j=lane&3 loads bytes j*16 + i*64, i=0..3 -> 16 rows x 64B perfectly
// coalesced per load instruction). 16 samples per pass, 3 passes (48 >= 45).
// Dot completed with 2 shfl_xor (quad-uniform after); cross-quad butterfly
// (xor 4,8,16,32) combines the 16 distinct quad values EXACTLY ONCE each
// (butterfly never crosses the intra-quad replication bits 0,1), so the sum
// needs no replication correction: 14 DS ops/wave vs 60 in the old scheme,
// and no shuffle->load-address dependency.
__global__ __launch_bounds__(256) void k_computeM(
        const float* __restrict__ Q, const float* __restrict__ K,
        const int* __restrict__ idx, float* __restrict__ M) {
    int w = (blockIdx.x * blockDim.x + threadIdx.x) >> 6; // global wave id
    w = __builtin_amdgcn_readfirstlane(w);                // wave-uniform -> SGPR
    int lane = threadIdx.x & 63;
    int q = w % LL;
    int bh = w / LL;            // b*HH + h
    int h = bh % HH, b = bh / HH;

    const float* Kbh = K + (size_t)(b * LL * HH + h) * DD;
    const size_t rowStride = (size_t)HH * DD; // 512 floats between key rows

    int j = lane & 3;    // 16B sub-segment within a row
    int sr = lane >> 2;  // sample slot within a pass (0..15)

    // Q fragments: lane j covers floats {j*4 + i*16 : i=0..3} of the Q row
    const float4* Qrow = (const float4*)(Q + qkv_idx(b, q, h, 0));
    float4 qf0 = Qrow[j];
    float4 qf1 = Qrow[j + 4];
    float4 qf2 = Qrow[j + 8];
    float4 qf3 = Qrow[j + 12];

    // sample indices for the 3 passes (clamped; invalid slots masked later)
    int ks0 = idx[q * UU + sr];
    int ks1 = idx[q * UU + 16 + sr];
    int s2 = 32 + sr;
    int ks2 = idx[q * UU + (s2 < UU ? s2 : 0)];

    float mval = -INFINITY, sval = 0.f;
    int kss[3] = {ks0, ks1, ks2};
#pragma unroll
    for (int p = 0; p < 3; ++p) {
        const float4* kp = (const float4*)(Kbh + (size_t)kss[p] * rowStride);
        float4 k0 = kp[j];
        float4 k1 = kp[j + 4];
        float4 k2 = kp[j + 8];
        float4 k3 = kp[j + 12];
        float part = 0.f;
        part = fmaf(qf0.x, k0.x, part);
        part = fmaf(qf0.y, k0.y, part);
        part = fmaf(qf0.z, k0.z, part);
        part = fmaf(qf0.w, k0.w, part);
        part = fmaf(qf1.x, k1.x, part);
        part = fmaf(qf1.y, k1.y, part);
        part = fmaf(qf1.z, k1.z, part);
        part = fmaf(qf1.w, k1.w, part);
        part = fmaf(qf2.x, k2.x, part);
        part = fmaf(qf2.y, k2.y, part);
        part = fmaf(qf2.z, k2.z, part);
        part = fmaf(qf2.w, k2.w, part);
        part = fmaf(qf3.x, k3.x, part);
        part = fmaf(qf3.y, k3.y, part);
        part = fmaf(qf3.z, k3.z, part);
        part = fmaf(qf3.w, k3.w, part);
        // complete the 64-d dot within the quad (bit-exact quad-uniform after)
        part += __shfl_xor(part, 1, 64);
        part += __shfl_xor(part, 2, 64);
        int s = p * 16 + sr;
        if (s < UU) { mval = fmaxf(mval, part); sval += part; }
    }
    // cross-quad butterfly over quad-index bits 2..5: each of the 16 quad
    // values is combined exactly once -> sval is the exact sum over samples.
    mval = fmaxf(mval, __shfl_xor(mval, 4, 64));
    sval += __shfl_xor(sval, 4, 64);
    mval = fmaxf(mval, __shfl_xor(mval, 8, 64));
    sval += __shfl_xor(sval, 8, 64);
    mval = fmaxf(mval, __shfl_xor(mval, 16, 64));
    sval += __shfl_xor(sval, 16, 64);
    mval = fmaxf(mval, __shfl_xor(mval, 32, 64));
    sval += __shfl_xor(sval, 32, 64);
    if (lane == 0) M[bh * LL + q] = mval - sval * (1.0f / LL);
}

// ---------------- Kernel 2: top-45 via 4-pass radix select ---------------------
// One block of 1024 threads per (b,h). Monotonic key transform, 8-bit MSD
// radix passes locate the exact 45th-largest key; collection pass emits all
// strictly-greater indices plus the lowest-index ties (jax.lax.top_k order
// is irrelevant downstream -- only the SET of indices matters).
__global__ __launch_bounds__(1024) void k_topk(
        const float* __restrict__ M, int* __restrict__ Mtop) {
    int bh = blockIdx.x;
    int t = threadIdx.x;
    __shared__ unsigned keys[LL];      // 16 KB
    __shared__ unsigned hist[256];
    __shared__ unsigned scanbuf[256];
    __shared__ unsigned sPrefix, sMask, sK, sBin;
    __shared__ int outCount, eqCount;
    __shared__ int eqIdx[64];

    for (int i = t; i < LL; i += 1024) {
        unsigned u = __float_as_uint(M[bh * LL + i]);
        keys[i] = (u & 0x80000000u) ? ~u : (u | 0x80000000u);
    }
    if (t == 0) { sPrefix = 0u; sMask = 0u; sK = UU; outCount = 0; eqCount = 0; }
    __syncthreads();

    for (int pass = 0; pass < 4; ++pass) {
        int shift = 24 - pass * 8;
        if (t < 256) hist[t] = 0u;
        __syncthreads();
        unsigned prefix = sPrefix, mask = sMask;
        for (int i = t; i < LL; i += 1024) {
            unsigned k = keys[i];
            if ((k & mask) == prefix)
                atomicAdd(&hist[(k >> shift) & 0xFFu], 1u);
        }
        __syncthreads();
        if (t < 256) scanbuf[t] = hist[t];
        __syncthreads();
        // suffix-sum: scanbuf[b] = count of keys with digit >= b (in subset)
        for (int off = 1; off < 256; off <<= 1) {
            unsigned v = 0u;
            if (t < 256 && t + off < 256) v = scanbuf[t + off];
            __syncthreads();
            if (t < 256) scanbuf[t] += v;
            __syncthreads();
        }
        if (t < 256) {
            unsigned k = sK;
            unsigned geq = scanbuf[t];
            unsigned gt = (t < 255) ? scanbuf[t + 1] : 0u;
            if (gt < k && geq >= k) sBin = (unsigned)t;
        }
        __syncthreads();
        if (t == 0) {
            unsigned b = sBin;
            unsigned gt = (b < 255u) ? scanbuf[b + 1] : 0u;
            sK -= gt;
            sPrefix |= (b << shift);
            sMask |= (0xFFu << shift);
        }
        __syncthreads();
    }
    unsigned T = sPrefix;
    int kEq = (int)sK;

    for (int i = t; i < LL; i += 1024) {
        unsigned k = keys[i];
        if (k > T) {
            int slot = atomicAdd(&outCount, 1);
            Mtop[bh * UU + slot] = i;
        } else if (k == T) {
            int e = atomicAdd(&eqCount, 1);
            if (e < 64) eqIdx[e] = i;
        }
    }
    __syncthreads();

    if (t == 0) {
        int base = outCount; // == UU - kEq
        int ec = eqCount;
        if (ec <= 64) {
            for (int s = 0; s < UU; ++s) { // s < kEq, bounded loop for compiler
                if (s >= kEq) break;
                int bi = -1, bv = LL + 2;
                for (int j = 0; j < ec; ++j) {
                    int v = eqIdx[j];
                    if (v < bv) { bv = v; bi = j; }
                }
                Mtop[bh * UU + base + s] = bv;
                eqIdx[bi] = LL + 2;
            }
        } else {
            // paranoid fallback (massive duplicate values): serial lowest-index
            int got = 0;
            for (int i = 0; i < LL && got < kEq; ++i)
                if (keys[i] == T) { Mtop[bh * UU + base + got] = i; ++got; }
        }
    }
}

// ---------------- Kernel 3: per-tile sums of V over l (for cumsum) -------------
__global__ __launch_bounds__(256) void k_tilesum(
        const float* __restrict__ V, float* __restrict__ tsum) {
    int blk = blockIdx.x; // ((b*HH+h)*NTILES + tile)
    int tile = blk % NTILES;
    int bh = blk / NTILES;
    int h = bh % HH, b = bh / HH;
    int d = threadIdx.x & 63, g = threadIdx.x >> 6; // g in 0..3
    const int CH = TILE / 4;                        // 32
    int l0 = tile * TILE + g * CH;
    float acc = 0.f;
    for (int i = 0; i < CH; ++i) acc += V[qkv_idx(b, l0 + i, h, d)];
    __shared__ float red[4][DD];
    red[g][d] = acc;
    __syncthreads();
    if (g == 0) tsum[blk * DD + d] = red[0][d] + red[1][d] + red[2][d] + red[3][d];
}

// ---------------- Kernel 4: exclusive scan of tile sums (32 tiles, serial) -----
__global__ void k_scantiles(float* __restrict__ tsum) {
    int bh = blockIdx.x;
    int d = threadIdx.x; // 64 threads
    float off = 0.f;
    for (int t = 0; t < NTILES; ++t) {
        int i = (bh * NTILES + t) * DD + d;
        float v = tsum[i];
        tsum[i] = off;
        off += v;
    }
}

// ---------------- Kernel 5: write cumsum(V) to out -----------------------------
__global__ __launch_bounds__(256) void k_cumsum(
        const float* __restrict__ V, const float* __restrict__ tsum,
        float* __restrict__ out) {
    int blk = blockIdx.x;
    int tile = blk % NTILES;
    int bh = blk / NTILES;
    int h = bh % HH, b = bh / HH;
    int d = threadIdx.x & 63, g = threadIdx.x >> 6;
    const int CH = TILE / 4;
    int l0 = tile * TILE + g * CH;

    __shared__ float red[4][DD];
    float acc = 0.f;
    for (int i = 0; i < CH; ++i) acc += V[qkv_idx(b, l0 + i, h, d)];
    red[g][d] = acc;
    __syncthreads();

    float off = tsum[blk * DD + d];
    for (int gg = 0; gg < g; ++gg) off += red[gg][d];

    float run = off;
    for (int i = 0; i < CH; ++i) {
        run += V[qkv_idx(b, l0 + i, h, d)];
        out[qkv_idx(b, l0 + i, h, d)] = run;
    }
}

// ---------------- Kernel 6a: split-K flash attention partials ------------------
__global__ __launch_bounds__(256) void k_attn_partial(
        const float* __restrict__ Q, const float* __restrict__ K,
        const float* __restrict__ V, const int* __restrict__ Mtop,
        float* __restrict__ mPart, float* __restrict__ lPart,
        float* __restrict__ Op) {
    int blk = blockIdx.x;      // bh * NC + c
    int c = blk % NC;
    int bh = blk / NC;
    int h = bh % HH, b = bh / HH;
    int k0 = c * CK;
    int t = threadIdx.x;

    __shared__ float Qs[48 * KSTR];   // 13056 B (rows 45..47 zeroed)
    __shared__ float Ks[CK * KSTR];   // 17408 B (reused for V in PV phase)
    __shared__ float Ss[UU * SSTR];   // 12240 B

    const size_t rowStride = (size_t)HH * DD; // 512 floats
    const float* Qbh = Q + (size_t)(b * LL * HH + h) * DD;
    const float* Kbh = K + (size_t)(b * LL * HH + h) * DD;
    const float* Vbh = V + (size_t)(b * LL * HH + h) * DD;

    for (int p = t; p < 48 * DD; p += 256) {
        int u = p >> 6, d = p & 63;
        float v = 0.f;
        if (u < UU) {
            int qi = Mtop[bh * UU + u];
            v = Qbh[(size_t)qi * rowStride + d] * 0.125f;
        }
        Qs[u * KSTR + d] = v;
    }
    for (int p = t; p < CK * 16; p += 256) {
        int row = p >> 4, i = p & 15;
        *(float4*)&Ks[row * KSTR + i * 4] =
            *(const float4*)&Kbh[(size_t)(k0 + row) * rowStride + i * 4];
    }
    __syncthreads();

    // --- scores GEMM: thread tile 3u x 4k ---
    int kq = t & 15, uq = t >> 4;
    int u0 = uq * 3;
    float acc[3][4];
#pragma unroll
    for (int i = 0; i < 3; ++i)
#pragma unroll
        for (int j = 0; j < 4; ++j) acc[i][j] = 0.f;

#pragma unroll 4
    for (int dd = 0; dd < 16; ++dd) {
        float4 qf[3];
#pragma unroll
        for (int i = 0; i < 3; ++i)
            qf[i] = *(const float4*)&Qs[(u0 + i) * KSTR + dd * 4];
        float4 kf[4];
#pragma unroll
        for (int j = 0; j < 4; ++j)
            kf[j] = *(const float4*)&Ks[(kq + 16 * j) * KSTR + dd * 4];
#pragma unroll
        for (int i = 0; i < 3; ++i)
#pragma unroll
            for (int j = 0; j < 4; ++j) {
                acc[i][j] = fmaf(qf[i].x, kf[j].x, acc[i][j]);
                acc[i][j] = fmaf(qf[i].y, kf[j].y, acc[i][j]);
                acc[i][j] = fmaf(qf[i].z, kf[j].z, acc[i][j]);
                acc[i][j] = fmaf(qf[i].w, kf[j].w, acc[i][j]);
            }
    }
#pragma unroll
    for (int i = 0; i < 3; ++i) {
        int u = u0 + i;
        if (u < UU)
#pragma unroll
            for (int j = 0; j < 4; ++j) Ss[u * SSTR + kq + 16 * j] = acc[i][j];
    }
    __syncthreads();

    // stage V chunk into the K buffer (no one reads Ks until next barrier)
    for (int p = t; p < CK * 16; p += 256) {
        int row = p >> 4, i = p & 15;
        *(float4*)&Ks[row * KSTR + i * 4] =
            *(const float4*)&Vbh[(size_t)(k0 + row) * rowStride + i * 4];
    }

    // --- chunk-local softmax: 4 threads per u ---
    if (t < UU * 4) {
        int u = t >> 2, qq = t & 3;
        float mloc = -INFINITY;
        for (int j = 0; j < CK / 4; ++j)
            mloc = fmaxf(mloc, Ss[u * SSTR + qq + 4 * j]);
        mloc = fmaxf(mloc, __shfl_xor(mloc, 1, 64));
        mloc = fmaxf(mloc, __shfl_xor(mloc, 2, 64));
        float lloc = 0.f;
        for (int j = 0; j < CK / 4; ++j) {
            int kk = qq + 4 * j;
            float e = __expf(Ss[u * SSTR + kk] - mloc);
            Ss[u * SSTR + kk] = e;
            lloc += e;
        }
        lloc += __shfl_xor(lloc, 1, 64);
        lloc += __shfl_xor(lloc, 2, 64);
        if (qq == 0) {
            mPart[(bh * NC + c) * UU + u] = mloc;
            lPart[(bh * NC + c) * UU + u] = lloc;
        }
    }
    __syncthreads();

    // --- PV GEMM: thread tile 3u x 4d ---
    int dq = t & 15;
    int d0 = dq * 4;
    if (u0 < UU) { // uq==15 idle
        float4 o[3];
#pragma unroll
        for (int i = 0; i < 3; ++i) o[i] = make_float4(0.f, 0.f, 0.f, 0.f);
#pragma unroll 4
        for (int kc = 0; kc < CK / 4; ++kc) {
            float4 vk[4];
#pragma unroll
            for (int jj = 0; jj < 4; ++jj)
                vk[jj] = *(const float4*)&Ks[(4 * kc + jj) * KSTR + d0];
#pragma unroll
            for (int i = 0; i < 3; ++i) {
                float4 pf = *(const float4*)&Ss[(u0 + i) * SSTR + 4 * kc];
                o[i].x = fmaf(pf.x, vk[0].x, o[i].x);
                o[i].y = fmaf(pf.x, vk[0].y, o[i].y);
                o[i].z = fmaf(pf.x, vk[0].z, o[i].z);
                o[i].w = fmaf(pf.x, vk[0].w, o[i].w);
                o[i].x = fmaf(pf.y, vk[1].x, o[i].x);
                o[i].y = fmaf(pf.y, vk[1].y, o[i].y);
                o[i].z = fmaf(pf.y, vk[1].z, o[i].z);
                o[i].w = fmaf(pf.y, vk[1].w, o[i].w);
                o[i].x = fmaf(pf.z, vk[2].x, o[i].x);
                o[i].y = fmaf(pf.z, vk[2].y, o[i].y);
                o[i].z = fmaf(pf.z, vk[2].z, o[i].z);
                o[i].w = fmaf(pf.z, vk[2].w, o[i].w);
                o[i].x = fmaf(pf.w, vk[3].x, o[i].x);
                o[i].y = fmaf(pf.w, vk[3].y, o[i].y);
                o[i].z = fmaf(pf.w, vk[3].z, o[i].z);
                o[i].w = fmaf(pf.w, vk[3].w, o[i].w);
            }
        }
#pragma unroll
        for (int i = 0; i < 3; ++i) {
            int u = u0 + i;
            *(float4*)&Op[((size_t)(bh * NC + c) * UU + u) * DD + d0] = o[i];
        }
    }
}

// ---------------- Kernel 6b: flash combine across chunks, scatter --------------
__global__ void k_attn_combine(
        const int* __restrict__ Mtop, const float* __restrict__ mPart,
        const float* __restrict__ lPart, const float* __restrict__ Op,
        float* __restrict__ out) {
    int blk = blockIdx.x; // bh*UU + u
    int u = blk % UU;
    int bh = blk / UU;
    int h = bh % HH, b = bh / HH;
    int d = threadIdx.x;  // 64
    float gm = -INFINITY;
    for (int c = 0; c < NC; ++c)
        gm = fmaxf(gm, mPart[(bh * NC + c) * UU + u]);
    float denom = 0.f, acc = 0.f;
    for (int c = 0; c < NC; ++c) {
        int pi = (bh * NC + c) * UU + u;
        float w = __expf(mPart[pi] - gm);
        denom = fmaf(lPart[pi], w, denom);
        acc = fmaf(w, Op[(size_t)pi * DD + d], acc);
    }
    int qi = Mtop[bh * UU + u];
    out[qkv_idx(b, qi, h, d)] = acc / denom;
}

// ---------------- Fallback: monolithic per-(bh,u) attention --------------------
__global__ __launch_bounds__(256) void k_attn_mono(
        const float* __restrict__ Q, const float* __restrict__ K,
        const float* __restrict__ V, const int* __restrict__ Mtop,
        float* __restrict__ out) {
    int blk = blockIdx.x; // bh*UU + u
    int u = blk % UU;
    int bh = blk / UU;
    int h = bh % HH, b = bh / HH;
    int qi = Mtop[bh * UU + u];
    int t = threadIdx.x;

    __shared__ float scores[LL];
    __shared__ float red[256];

    const float4* qp = (const float4*)(Q + qkv_idx(b, qi, h, 0));
    float4 qreg[16];
#pragma unroll
    for (int i = 0; i < 16; ++i) {
        float4 v = qp[i];
        v.x *= 0.125f; v.y *= 0.125f; v.z *= 0.125f; v.w *= 0.125f;
        qreg[i] = v;
    }

    float lmax = -INFINITY;
    for (int k = t; k < LL; k += 256) {
        const float4* kr = (const float4*)(K + qkv_idx(b, k, h, 0));
        float dot = 0.f;
#pragma unroll
        for (int i = 0; i < 16; ++i) {
            float4 kk = kr[i];
            dot = fmaf(qreg[i].x, kk.x, dot);
            dot = fmaf(qreg[i].y, kk.y, dot);
            dot = fmaf(qreg[i].z, kk.z, dot);
            dot = fmaf(qreg[i].w, kk.w, dot);
        }
        scores[k] = dot;
        lmax = fmaxf(lmax, dot);
    }
    red[t] = lmax;
    __syncthreads();
    for (int off = 128; off >= 1; off >>= 1) {
        if (t < off) red[t] = fmaxf(red[t], red[t + off]);
        __syncthreads();
    }
    float smax = red[0];
    __syncthreads();

    float lsum = 0.f;
    for (int k = t; k < LL; k += 256) {
        float e = __expf(scores[k] - smax);
        scores[k] = e;
        lsum += e;
    }
    red[t] = lsum;
    __syncthreads();
    for (int off = 128; off >= 1; off >>= 1) {
        if (t < off) red[t] += red[t + off];
        __syncthreads();
    }
    float denom = red[0];
    __syncthreads();

    int d = t & 63, g = t >> 6;
    const float4* sc4 = (const float4*)scores;
    float acc = 0.f;
    for (int kb = g; kb < LL / 4; kb += 4) {
        float4 s4 = sc4[kb];
        int kk0 = kb * 4;
        acc = fmaf(s4.x, V[qkv_idx(b, kk0 + 0, h, d)], acc);
        acc = fmaf(s4.y, V[qkv_idx(b, kk0 + 1, h, d)], acc);
        acc = fmaf(s4.z, V[qkv_idx(b, kk0 + 2, h, d)], acc);
        acc = fmaf(s4.w, V[qkv_idx(b, kk0 + 3, h, d)], acc);
    }
    red[t] = acc;
    __syncthreads();
    if (g == 0) {
        float s = red[d] + red[64 + d] + red[128 + d] + red[192 + d];
        out[qkv_idx(b, qi, h, d)] = s / denom;
    }
}

extern "C" void kernel_launch(void* const* d_in, const int* in_sizes, int n_in,
                              void* d_out, int out_size, void* d_ws, size_t ws_size,
                              hipStream_t stream) {
    const float* Q = (const float*)d_in[0];
    const float* K = (const float*)d_in[1];
    const float* V = (const float*)d_in[2];
    const int* idx = (const int*)d_in[3];
    float* out = (float*)d_out;

    float* ws = (float*)d_ws;

    // workspace layout (floats)
    const size_t M_off = 0;                           // 65536
    const size_t tsum_off = 65536;                    // 32768
    const size_t mP_off = 98304;                      // 16*64*45 = 46080
    const size_t lP_off = 144384;                     // 46080
    const size_t top_off = 190464;                    // 720 ints (reserve 1024)
    const size_t Op_off = 191488;                     // 16*64*45*64 = 2949120
    const size_t need = (Op_off + (size_t)BB * HH * NC * UU * DD) * 4;

    float* M = ws + M_off;
    float* tsum = ws + tsum_off;

    if (ws_size >= need) {
        float* mPart = ws + mP_off;
        float* lPart = ws + lP_off;
        int* Mtop = (int*)(ws + top_off);
        float* Op = ws + Op_off;

        k_computeM<<<BB * HH * LL / 4, 256, 0, stream>>>(Q, K, idx, M);
        k_topk<<<BB * HH, 1024, 0, stream>>>(M, Mtop);
        k_attn_partial<<<BB * HH * NC, 256, 0, stream>>>(Q, K, V, Mtop,
                                                         mPart, lPart, Op);
        k_tilesum<<<BB * HH * NTILES, 256, 0, stream>>>(V, tsum);
        k_scantiles<<<BB * HH, 64, 0, stream>>>(tsum);
        k_cumsum<<<BB * HH * NTILES, 256, 0, stream>>>(V, tsum, out);
        k_attn_combine<<<BB * HH * UU, 64, 0, stream>>>(Mtop, mPart, lPart,
                                                        Op, out);
    } else {
        // compact fallback layout
        int* Mtop = (int*)(ws + 65536);
        float* tsum2 = ws + 65536 + 1024;
        k_computeM<<<BB * HH * LL / 4, 256, 0, stream>>>(Q, K, idx, M);
        k_topk<<<BB * HH, 1024, 0, stream>>>(M, Mtop);
        k_tilesum<<<BB * HH * NTILES, 256, 0, stream>>>(V, tsum2);
        k_scantiles<<<BB * HH, 64, 0, stream>>>(tsum2);
        k_cumsum<<<BB * HH * NTILES, 256, 0, stream>>>(V, tsum2, out);
        k_attn_mono<<<BB * HH * UU, 256, 0, stream>>>(Q, K, V, Mtop, out);
    }
}

// Round 3
// 219.640 us; speedup vs baseline: 1.0210x; 1.0210x over previous
//
#include <hip/hip_runtime.h>
#include <math.h>

#define BB 2
#define LL 4096
#define HH 8
#define DD 64
#define UU 45
#define TILE 128
#define NTILES (LL / TILE) // 32

// split-K attention config
#define NC 64              // key chunks
#define CK (LL / NC)       // 64 keys per chunk
#define KSTR 68            // padded LDS row stride (floats) for K/V/Q tiles
#define SSTR 68            // padded LDS row stride for scores (CK=64 + 4)

__device__ __forceinline__ int qkv_idx(int b, int l, int h, int d) {
    return ((b * LL + l) * HH + h) * DD + d;
}

// ---------------- Kernel 1: sparsity metric M[b,h,q] ---------------------------
// One wave per query. 16 lanes cooperate per sampled K row (4 rows per load
// instruction -> 4 contiguous 256B runs: segment-optimal, since a K row is
// 256B and samples are random). Round-2 lesson: 4-lane/row layout (16x64B
// scattered runs) is ~22% slower despite fewer shuffles -- memory-pipe
// segment count dominates, VALU work hides latency for free.
__global__ __launch_bounds__(256) void k_computeM(
        const float* __restrict__ Q, const float* __restrict__ K,
        const int* __restrict__ idx, float* __restrict__ M) {
    int w = (blockIdx.x * blockDim.x + threadIdx.x) >> 6; // global wave id
    int lane = threadIdx.x & 63;
    int q = w % LL;
    int bh = w / LL;            // b*HH + h
    int h = bh % HH, b = bh / HH;

    const float* Kbh = K + (size_t)(b * LL * HH + h) * DD;
    const size_t rowStride = (size_t)HH * DD; // 512 floats between key rows

    float qv = Q[qkv_idx(b, q, h, lane)];     // lane = d
    int myks = idx[q * UU + (lane < UU ? lane : 0)];

    int r = lane >> 4;    // which of 4 rows this lane helps load
    int c16 = lane & 15;  // position within 16-lane row group

    float q0 = __shfl(qv, c16 * 4 + 0, 64);
    float q1 = __shfl(qv, c16 * 4 + 1, 64);
    float q2 = __shfl(qv, c16 * 4 + 2, 64);
    float q3 = __shfl(qv, c16 * 4 + 3, 64);

    float mval = -INFINITY, sval = 0.f;
#pragma unroll
    for (int g = 0; g < 12; ++g) {           // 12 groups x 4 rows = 48 >= 45
        int s = g * 4 + r;
        int ks = __shfl(myks, s, 64);        // s <= 47 < 64; invalid s -> safe row
        const float4* kp = (const float4*)(Kbh + (size_t)ks * rowStride);
        float4 kk = kp[c16];
        float part = fmaf(kk.x, q0, fmaf(kk.y, q1, fmaf(kk.z, q2, kk.w * q3)));
        part += __shfl_xor(part, 8, 64);
        part += __shfl_xor(part, 4, 64);
        part += __shfl_xor(part, 2, 64);
        part += __shfl_xor(part, 1, 64);
        if (s < UU) { mval = fmaxf(mval, part); sval += part; }
    }
    // combine the 4 row groups (lanes differing in bits 4,5)
    mval = fmaxf(mval, __shfl_xor(mval, 16, 64));
    sval += __shfl_xor(sval, 16, 64);
    mval = fmaxf(mval, __shfl_xor(mval, 32, 64));
    sval += __shfl_xor(sval, 32, 64);
    if (lane == 0) M[bh * LL + q] = mval - sval * (1.0f / LL);
}

// ---------------- Kernel 2: top-45 via 4-pass radix select ---------------------
// One block of 1024 threads per (b,h). Monotonic key transform, 8-bit MSD
// radix passes locate the exact 45th-largest key; collection pass emits all
// strictly-greater indices plus the lowest-index ties. Additionally emits a
// 4096-bit selection bitmap (selmap) so k_cumsum can skip the selected rows
// (k_attn_combine writes them), removing one kernel launch from the chain.
__global__ __launch_bounds__(1024) void k_topk(
        const float* __restrict__ M, int* __restrict__ Mtop,
        unsigned* __restrict__ selmap) {
    int bh = blockIdx.x;
    int t = threadIdx.x;
    __shared__ unsigned keys[LL];      // 16 KB
    __shared__ unsigned hist[256];
    __shared__ unsigned scanbuf[256];
    __shared__ unsigned sPrefix, sMask, sK, sBin;
    __shared__ int outCount, eqCount;
    __shared__ int eqIdx[64];

    for (int i = t; i < LL; i += 1024) {
        unsigned u = __float_as_uint(M[bh * LL + i]);
        keys[i] = (u & 0x80000000u) ? ~u : (u | 0x80000000u);
    }
    if (selmap != nullptr && t < 128) selmap[bh * 128 + t] = 0u;
    if (t == 0) { sPrefix = 0u; sMask = 0u; sK = UU; outCount = 0; eqCount = 0; }
    __syncthreads();

    for (int pass = 0; pass < 4; ++pass) {
        int shift = 24 - pass * 8;
        if (t < 256) hist[t] = 0u;
        __syncthreads();
        unsigned prefix = sPrefix, mask = sMask;
        for (int i = t; i < LL; i += 1024) {
            unsigned k = keys[i];
            if ((k & mask) == prefix)
                atomicAdd(&hist[(k >> shift) & 0xFFu], 1u);
        }
        __syncthreads();
        if (t < 256) scanbuf[t] = hist[t];
        __syncthreads();
        // suffix-sum: scanbuf[b] = count of keys with digit >= b (in subset)
        for (int off = 1; off < 256; off <<= 1) {
            unsigned v = 0u;
            if (t < 256 && t + off < 256) v = scanbuf[t + off];
            __syncthreads();
            if (t < 256) scanbuf[t] += v;
            __syncthreads();
        }
        if (t < 256) {
            unsigned k = sK;
            unsigned geq = scanbuf[t];
            unsigned gt = (t < 255) ? scanbuf[t + 1] : 0u;
            if (gt < k && geq >= k) sBin = (unsigned)t;
        }
        __syncthreads();
        if (t == 0) {
            unsigned b = sBin;
            unsigned gt = (b < 255u) ? scanbuf[b + 1] : 0u;
            sK -= gt;
            sPrefix |= (b << shift);
            sMask |= (0xFFu << shift);
        }
        __syncthreads();
    }
    unsigned T = sPrefix;
    int kEq = (int)sK;

    for (int i = t; i < LL; i += 1024) {
        unsigned k = keys[i];
        if (k > T) {
            int slot = atomicAdd(&outCount, 1);
            Mtop[bh * UU + slot] = i;
        } else if (k == T) {
            int e = atomicAdd(&eqCount, 1);
            if (e < 64) eqIdx[e] = i;
        }
    }
    __syncthreads();

    if (t == 0) {
        int base = outCount; // == UU - kEq
        int ec = eqCount;
        if (ec <= 64) {
            for (int s = 0; s < UU; ++s) { // s < kEq, bounded loop for compiler
                if (s >= kEq) break;
                int bi = -1, bv = LL + 2;
                for (int j = 0; j < ec; ++j) {
                    int v = eqIdx[j];
                    if (v < bv) { bv = v; bi = j; }
                }
                Mtop[bh * UU + base + s] = bv;
                eqIdx[bi] = LL + 2;
            }
        } else {
            // paranoid fallback (massive duplicate values): serial lowest-index
            int got = 0;
            for (int i = 0; i < LL && got < kEq; ++i)
                if (keys[i] == T) { Mtop[bh * UU + base + got] = i; ++got; }
        }
    }
    __syncthreads();
    if (selmap != nullptr && t < UU) {
        int qi = Mtop[bh * UU + t];
        atomicOr(&selmap[bh * 128 + (qi >> 5)], 1u << (qi & 31));
    }
}

// ---------------- Kernel 3: per-tile RAW sums of V over l (for cumsum) ---------
__global__ __launch_bounds__(256) void k_tilesum(
        const float* __restrict__ V, float* __restrict__ tsum) {
    int blk = blockIdx.x; // ((b*HH+h)*NTILES + tile)
    int tile = blk % NTILES;
    int bh = blk / NTILES;
    int h = bh % HH, b = bh / HH;
    int d = threadIdx.x & 63, g = threadIdx.x >> 6; // g in 0..3
    const int CH = TILE / 4;                        // 32
    int l0 = tile * TILE + g * CH;
    float acc = 0.f;
    for (int i = 0; i < CH; ++i) acc += V[qkv_idx(b, l0 + i, h, d)];
    __shared__ float red[4][DD];
    red[g][d] = acc;
    __syncthreads();
    if (g == 0) tsum[blk * DD + d] = red[0][d] + red[1][d] + red[2][d] + red[3][d];
}

// ---------------- Kernel 4: cumsum(V) -> out, with in-block tile prefix --------
// Computes the exclusive prefix over raw tile sums itself (<=31 coalesced
// 256B loads) -- replaces the latency-serial k_scantiles kernel. Skips rows
// flagged in selmap (those are written by k_attn_combine, which now runs
// BEFORE this kernel).
__global__ __launch_bounds__(256) void k_cumsum(
        const float* __restrict__ V, const float* __restrict__ tsum,
        const unsigned* __restrict__ selmap, float* __restrict__ out) {
    int blk = blockIdx.x;
    int tile = blk % NTILES;
    int bh = blk / NTILES;
    int h = bh % HH, b = bh / HH;
    int t = threadIdx.x;
    int d = t & 63, g = t >> 6;
    const int CH = TILE / 4;
    int l0 = tile * TILE + g * CH;

    __shared__ float red[4][DD];
    __shared__ float pref[DD];
    float acc = 0.f;
    for (int i = 0; i < CH; ++i) acc += V[qkv_idx(b, l0 + i, h, d)];
    red[g][d] = acc;
    if (t < DD) {
        float off = 0.f;
        for (int tt = 0; tt < tile; ++tt)
            off += tsum[(bh * NTILES + tt) * DD + t];
        pref[t] = off;
    }
    __syncthreads();

    float off = pref[d];
    for (int gg = 0; gg < g; ++gg) off += red[gg][d];

    // rows l0..l0+31 share one bitmap word: l>>5 == tile*4+g
    unsigned selw = (selmap != nullptr) ? selmap[bh * 128 + (l0 >> 5)] : 0u;

    float run = off;
    for (int i = 0; i < CH; ++i) {
        run += V[qkv_idx(b, l0 + i, h, d)];
        if (!((selw >> i) & 1u))
            out[qkv_idx(b, l0 + i, h, d)] = run;
    }
}

// ---------------- Kernel 5a: split-K flash attention partials ------------------
__global__ __launch_bounds__(256) void k_attn_partial(
        const float* __restrict__ Q, const float* __restrict__ K,
        const float* __restrict__ V, const int* __restrict__ Mtop,
        float* __restrict__ mPart, float* __restrict__ lPart,
        float* __restrict__ Op) {
    int blk = blockIdx.x;      // bh * NC + c
    int c = blk % NC;
    int bh = blk / NC;
    int h = bh % HH, b = bh / HH;
    int k0 = c * CK;
    int t = threadIdx.x;

    __shared__ float Qs[48 * KSTR];   // 13056 B (rows 45..47 zeroed)
    __shared__ float Ks[CK * KSTR];   // 17408 B (reused for V in PV phase)
    __shared__ float Ss[UU * SSTR];   // 12240 B

    const size_t rowStride = (size_t)HH * DD; // 512 floats
    const float* Qbh = Q + (size_t)(b * LL * HH + h) * DD;
    const float* Kbh = K + (size_t)(b * LL * HH + h) * DD;
    const float* Vbh = V + (size_t)(b * LL * HH + h) * DD;

    for (int p = t; p < 48 * DD; p += 256) {
        int u = p >> 6, d = p & 63;
        float v = 0.f;
        if (u < UU) {
            int qi = Mtop[bh * UU + u];
            v = Qbh[(size_t)qi * rowStride + d] * 0.125f;
        }
        Qs[u * KSTR + d] = v;
    }
    for (int p = t; p < CK * 16; p += 256) {
        int row = p >> 4, i = p & 15;
        *(float4*)&Ks[row * KSTR + i * 4] =
            *(const float4*)&Kbh[(size_t)(k0 + row) * rowStride + i * 4];
    }
    __syncthreads();

    // --- scores GEMM: thread tile 3u x 4k ---
    int kq = t & 15, uq = t >> 4;
    int u0 = uq * 3;
    float acc[3][4];
#pragma unroll
    for (int i = 0; i < 3; ++i)
#pragma unroll
        for (int j = 0; j < 4; ++j) acc[i][j] = 0.f;

#pragma unroll 4
    for (int dd = 0; dd < 16; ++dd) {
        float4 qf[3];
#pragma unroll
        for (int i = 0; i < 3; ++i)
            qf[i] = *(const float4*)&Qs[(u0 + i) * KSTR + dd * 4];
        float4 kf[4];
#pragma unroll
        for (int j = 0; j < 4; ++j)
            kf[j] = *(const float4*)&Ks[(kq + 16 * j) * KSTR + dd * 4];
#pragma unroll
        for (int i = 0; i < 3; ++i)
#pragma unroll
            for (int j = 0; j < 4; ++j) {
                acc[i][j] = fmaf(qf[i].x, kf[j].x, acc[i][j]);
                acc[i][j] = fmaf(qf[i].y, kf[j].y, acc[i][j]);
                acc[i][j] = fmaf(qf[i].z, kf[j].z, acc[i][j]);
                acc[i][j] = fmaf(qf[i].w, kf[j].w, acc[i][j]);
            }
    }
#pragma unroll
    for (int i = 0; i < 3; ++i) {
        int u = u0 + i;
        if (u < UU)
#pragma unroll
            for (int j = 0; j < 4; ++j) Ss[u * SSTR + kq + 16 * j] = acc[i][j];
    }
    __syncthreads();

    // stage V chunk into the K buffer (no one reads Ks until next barrier)
    for (int p = t; p < CK * 16; p += 256) {
        int row = p >> 4, i = p & 15;
        *(float4*)&Ks[row * KSTR + i * 4] =
            *(const float4*)&Vbh[(size_t)(k0 + row) * rowStride + i * 4];
    }

    // --- chunk-local softmax: 4 threads per u ---
    if (t < UU * 4) {
        int u = t >> 2, qq = t & 3;
        float mloc = -INFINITY;
        for (int j = 0; j < CK / 4; ++j)
            mloc = fmaxf(mloc, Ss[u * SSTR + qq + 4 * j]);
        mloc = fmaxf(mloc, __shfl_xor(mloc, 1, 64));
        mloc = fmaxf(mloc, __shfl_xor(mloc, 2, 64));
        float lloc = 0.f;
        for (int j = 0; j < CK / 4; ++j) {
            int kk = qq + 4 * j;
            float e = __expf(Ss[u * SSTR + kk] - mloc);
            Ss[u * SSTR + kk] = e;
            lloc += e;
        }
        lloc += __shfl_xor(lloc, 1, 64);
        lloc += __shfl_xor(lloc, 2, 64);
        if (qq == 0) {
            mPart[(bh * NC + c) * UU + u] = mloc;
            lPart[(bh * NC + c) * UU + u] = lloc;
        }
    }
    __syncthreads();

    // --- PV GEMM: thread tile 3u x 4d ---
    int dq = t & 15;
    int d0 = dq * 4;
    if (u0 < UU) { // uq==15 idle
        float4 o[3];
#pragma unroll
        for (int i = 0; i < 3; ++i) o[i] = make_float4(0.f, 0.f, 0.f, 0.f);
#pragma unroll 4
        for (int kc = 0; kc < CK / 4; ++kc) {
            float4 vk[4];
#pragma unroll
            for (int jj = 0; jj < 4; ++jj)
                vk[jj] = *(const float4*)&Ks[(4 * kc + jj) * KSTR + d0];
#pragma unroll
            for (int i = 0; i < 3; ++i) {
                float4 pf = *(const float4*)&Ss[(u0 + i) * SSTR + 4 * kc];
                o[i].x = fmaf(pf.x, vk[0].x, o[i].x);
                o[i].y = fmaf(pf.x, vk[0].y, o[i].y);
                o[i].z = fmaf(pf.x, vk[0].z, o[i].z);
                o[i].w = fmaf(pf.x, vk[0].w, o[i].w);
                o[i].x = fmaf(pf.y, vk[1].x, o[i].x);
                o[i].y = fmaf(pf.y, vk[1].y, o[i].y);
                o[i].z = fmaf(pf.y, vk[1].z, o[i].z);
                o[i].w = fmaf(pf.y, vk[1].w, o[i].w);
                o[i].x = fmaf(pf.z, vk[2].x, o[i].x);
                o[i].y = fmaf(pf.z, vk[2].y, o[i].y);
                o[i].z = fmaf(pf.z, vk[2].z, o[i].z);
                o[i].w = fmaf(pf.z, vk[2].w, o[i].w);
                o[i].x = fmaf(pf.w, vk[3].x, o[i].x);
                o[i].y = fmaf(pf.w, vk[3].y, o[i].y);
                o[i].z = fmaf(pf.w, vk[3].z, o[i].z);
                o[i].w = fmaf(pf.w, vk[3].w, o[i].w);
            }
        }
#pragma unroll
        for (int i = 0; i < 3; ++i) {
            int u = u0 + i;
            *(float4*)&Op[((size_t)(bh * NC + c) * UU + u) * DD + d0] = o[i];
        }
    }
}

// ---------------- Kernel 5b: flash combine across chunks, scatter --------------
// Runs BEFORE k_cumsum now; cumsum skips these rows via selmap.
__global__ void k_attn_combine(
        const int* __restrict__ Mtop, const float* __restrict__ mPart,
        const float* __restrict__ lPart, const float* __restrict__ Op,
        float* __restrict__ out) {
    int blk = blockIdx.x; // bh*UU + u
    int u = blk % UU;
    int bh = blk / UU;
    int h = bh % HH, b = bh / HH;
    int d = threadIdx.x;  // 64
    float gm = -INFINITY;
    for (int c = 0; c < NC; ++c)
        gm = fmaxf(gm, mPart[(bh * NC + c) * UU + u]);
    float denom = 0.f, acc = 0.f;
    for (int c = 0; c < NC; ++c) {
        int pi = (bh * NC + c) * UU + u;
        float w = __expf(mPart[pi] - gm);
        denom = fmaf(lPart[pi], w, denom);
        acc = fmaf(w, Op[(size_t)pi * DD + d], acc);
    }
    int qi = Mtop[bh * UU + u];
    out[qkv_idx(b, qi, h, d)] = acc / denom;
}

// ---------------- Fallback: monolithic per-(bh,u) attention --------------------
__global__ __launch_bounds__(256) void k_attn_mono(
        const float* __restrict__ Q, const float* __restrict__ K,
        const float* __restrict__ V, const int* __restrict__ Mtop,
        float* __restrict__ out) {
    int blk = blockIdx.x; // bh*UU + u
    int u = blk % UU;
    int bh = blk / UU;
    int h = bh % HH, b = bh / HH;
    int qi = Mtop[bh * UU + u];
    int t = threadIdx.x;

    __shared__ float scores[LL];
    __shared__ float red[256];

    const float4* qp = (const float4*)(Q + qkv_idx(b, qi, h, 0));
    float4 qreg[16];
#pragma unroll
    for (int i = 0; i < 16; ++i) {
        float4 v = qp[i];
        v.x *= 0.125f; v.y *= 0.125f; v.z *= 0.125f; v.w *= 0.125f;
        qreg[i] = v;
    }

    float lmax = -INFINITY;
    for (int k = t; k < LL; k += 256) {
        const float4* kr = (const float4*)(K + qkv_idx(b, k, h, 0));
        float dot = 0.f;
#pragma unroll
        for (int i = 0; i < 16; ++i) {
            float4 kk = kr[i];
            dot = fmaf(qreg[i].x, kk.x, dot);
            dot = fmaf(qreg[i].y, kk.y, dot);
            dot = fmaf(qreg[i].z, kk.z, dot);
            dot = fmaf(qreg[i].w, kk.w, dot);
        }
        scores[k] = dot;
        lmax = fmaxf(lmax, dot);
    }
    red[t] = lmax;
    __syncthreads();
    for (int off = 128; off >= 1; off >>= 1) {
        if (t < off) red[t] = fmaxf(red[t], red[t + off]);
        __syncthreads();
    }
    float smax = red[0];
    __syncthreads();

    float lsum = 0.f;
    for (int k = t; k < LL; k += 256) {
        float e = __expf(scores[k] - smax);
        scores[k] = e;
        lsum += e;
    }
    red[t] = lsum;
    __syncthreads();
    for (int off = 128; off >= 1; off >>= 1) {
        if (t < off) red[t] += red[t + off];
        __syncthreads();
    }
    float denom = red[0];
    __syncthreads();

    int d = t & 63, g = t >> 6;
    const float4* sc4 = (const float4*)scores;
    float acc = 0.f;
    for (int kb = g; kb < LL / 4; kb += 4) {
        float4 s4 = sc4[kb];
        int kk0 = kb * 4;
        acc = fmaf(s4.x, V[qkv_idx(b, kk0 + 0, h, d)], acc);
        acc = fmaf(s4.y, V[qkv_idx(b, kk0 + 1, h, d)], acc);
        acc = fmaf(s4.z, V[qkv_idx(b, kk0 + 2, h, d)], acc);
        acc = fmaf(s4.w, V[qkv_idx(b, kk0 + 3, h, d)], acc);
    }
    red[t] = acc;
    __syncthreads();
    if (g == 0) {
        float s = red[d] + red[64 + d] + red[128 + d] + red[192 + d];
        out[qkv_idx(b, qi, h, d)] = s / denom;
    }
}

extern "C" void kernel_launch(void* const* d_in, const int* in_sizes, int n_in,
                              void* d_out, int out_size, void* d_ws, size_t ws_size,
                              hipStream_t stream) {
    const float* Q = (const float*)d_in[0];
    const float* K = (const float*)d_in[1];
    const float* V = (const float*)d_in[2];
    const int* idx = (const int*)d_in[3];
    float* out = (float*)d_out;

    float* ws = (float*)d_ws;

    // workspace layout (floats)
    const size_t M_off = 0;                           // 65536
    const size_t tsum_off = 65536;                    // 32768
    const size_t mP_off = 98304;                      // 16*64*45 = 46080
    const size_t lP_off = 144384;                     // 46080
    const size_t top_off = 190464;                    // 720 ints (reserve 1024)
    const size_t sel_off = 191488;                    // 16*128 uints (2048)
    const size_t Op_off = 193536;                     // 16*64*45*64 = 2949120
    const size_t need = (Op_off + (size_t)BB * HH * NC * UU * DD) * 4;

    float* M = ws + M_off;
    float* tsum = ws + tsum_off;

    if (ws_size >= need) {
        float* mPart = ws + mP_off;
        float* lPart = ws + lP_off;
        int* Mtop = (int*)(ws + top_off);
        unsigned* selmap = (unsigned*)(ws + sel_off);
        float* Op = ws + Op_off;

        k_computeM<<<BB * HH * LL / 4, 256, 0, stream>>>(Q, K, idx, M);
        k_topk<<<BB * HH, 1024, 0, stream>>>(M, Mtop, selmap);
        k_attn_partial<<<BB * HH * NC, 256, 0, stream>>>(Q, K, V, Mtop,
                                                         mPart, lPart, Op);
        k_tilesum<<<BB * HH * NTILES, 256, 0, stream>>>(V, tsum);
        k_attn_combine<<<BB * HH * UU, 64, 0, stream>>>(Mtop, mPart, lPart,
                                                        Op, out);
        k_cumsum<<<BB * HH * NTILES, 256, 0, stream>>>(V, tsum, selmap, out);
    } else {
        // compact fallback layout
        int* Mtop = (int*)(ws + 65536);
        float* tsum2 = ws + 65536 + 1024;
        k_computeM<<<BB * HH * LL / 4, 256, 0, stream>>>(Q, K, idx, M);
        k_topk<<<BB * HH, 1024, 0, stream>>>(M, Mtop, (unsigned*)nullptr);
        k_tilesum<<<BB * HH * NTILES, 256, 0, stream>>>(V, tsum2);
        k_cumsum<<<BB * HH * NTILES, 256, 0, stream>>>(V, tsum2,
                                                       (const unsigned*)nullptr,
                                                       out);
        k_attn_mono<<<BB * HH * UU, 256, 0, stream>>>(Q, K, V, Mtop, out);
    }
}

// Round 6
// 208.427 us; speedup vs baseline: 1.0760x; 1.0538x over previous
//
#include <hip/hip_runtime.h>
#include <math.h>

#define BB 2
#define LL 4096
#define HH 8
#define DD 64
#define UU 45
#define TILE 128
#define NTILES (LL / TILE) // 32

// split-K attention config
#define NC 64              // key chunks
#define CK (LL / NC)       // 64 keys per chunk
#define KSTR 68            // padded LDS row stride (floats) for K/V/Q tiles
#define SSTR 68            // padded LDS row stride for scores (CK=64 + 4)

__device__ __forceinline__ int qkv_idx(int b, int l, int h, int d) {
    return ((b * LL + l) * HH + h) * DD + d;
}

// DPP all-reduce helper: v += rotate-within-16-lane-row(v, N). VALU pipe only.
template <int CTRL>
__device__ __forceinline__ float dpp_add(float v) {
    int x = __builtin_amdgcn_update_dpp(0, __float_as_int(v), CTRL, 0xF, 0xF,
                                        true);
    return v + __int_as_float(x);
}

// ---------------- Kernel 1: sparsity metric M[b,h,q] ---------------------------
// One wave per query. 16 lanes cooperate per sampled K row (4 rows per load
// instruction -> 4 contiguous 256B runs: segment-optimal). Round-4 change:
// the kernel was DS-pipe-bound (68 cross-lane ops/wave ~= 42us/CU). Now:
//  - Q fragment loaded directly (float4 at d=c16*4, 4-way broadcast row read)
//  - ks loaded directly from idx (L1-resident row) instead of bpermute
//  - 16-lane dot reduce via DPP row_ror add chain (VALU pipe, zero DS ops)
// leaving only 4 DS ops/wave (final cross-row xor16/32 combine).
__global__ __launch_bounds__(256) void k_computeM(
        const float* __restrict__ Q, const float* __restrict__ K,
        const int* __restrict__ idx, float* __restrict__ M) {
    int w = (blockIdx.x * blockDim.x + threadIdx.x) >> 6; // global wave id
    int lane = threadIdx.x & 63;
    int q = w % LL;
    int bh = w / LL;            // b*HH + h
    int h = bh % HH, b = bh / HH;

    const float* Kbh = K + (size_t)(b * LL * HH + h) * DD;
    const size_t rowStride = (size_t)HH * DD; // 512 floats between key rows

    int r = lane >> 4;    // which of 4 rows this lane helps load (DPP row id)
    int c16 = lane & 15;  // position within 16-lane row group

    // lane covers floats c16*4 .. c16*4+3 of both Q row and sampled K rows
    const float4 qf = *(const float4*)(Q + qkv_idx(b, q, h, c16 * 4));
    const int* idxRow = idx + q * UU;

    float mval = -INFINITY, sval = 0.f;
#pragma unroll
    for (int g = 0; g < 12; ++g) {           // 12 groups x 4 rows = 48 >= 45
        int s = g * 4 + r;
        int ks = idxRow[s < UU ? s : 0];     // clamped (row-end OOB guard)
        const float4* kp = (const float4*)(Kbh + (size_t)ks * rowStride);
        float4 kk = kp[c16];
        float part = fmaf(kk.x, qf.x,
                     fmaf(kk.y, qf.y, fmaf(kk.z, qf.z, kk.w * qf.w)));
        // all-reduce across the 16-lane row: DPP rotations (VALU, no DS pipe)
        part = dpp_add<0x128>(part); // row_ror:8
        part = dpp_add<0x124>(part); // row_ror:4
        part = dpp_add<0x122>(part); // row_ror:2
        part = dpp_add<0x121>(part); // row_ror:1
        if (s < UU) { mval = fmaxf(mval, part); sval += part; }
    }
    // combine the 4 row groups (lanes differing in bits 4,5)
    mval = fmaxf(mval, __shfl_xor(mval, 16, 64));
    sval += __shfl_xor(sval, 16, 64);
    mval = fmaxf(mval, __shfl_xor(mval, 32, 64));
    sval += __shfl_xor(sval, 32, 64);
    if (lane == 0) M[bh * LL + q] = mval - sval * (1.0f / LL);
}

// ---------------- Kernel 2: top-45 via 4-pass radix select ---------------------
// One block of 1024 threads per (b,h). Monotonic key transform, 8-bit MSD
// radix passes locate the exact 45th-largest key; collection pass emits all
// strictly-greater indices plus the lowest-index ties. Additionally emits a
// 4096-bit selection bitmap (selmap) so k_cumsum can skip the selected rows
// (k_attn_combine writes them), removing one kernel launch from the chain.
__global__ __launch_bounds__(1024) void k_topk(
        const float* __restrict__ M, int* __restrict__ Mtop,
        unsigned* __restrict__ selmap) {
    int bh = blockIdx.x;
    int t = threadIdx.x;
    __shared__ unsigned keys[LL];      // 16 KB
    __shared__ unsigned hist[256];
    __shared__ unsigned scanbuf[256];
    __shared__ unsigned sPrefix, sMask, sK, sBin;
    __shared__ int outCount, eqCount;
    __shared__ int eqIdx[64];

    for (int i = t; i < LL; i += 1024) {
        unsigned u = __float_as_uint(M[bh * LL + i]);
        keys[i] = (u & 0x80000000u) ? ~u : (u | 0x80000000u);
    }
    if (selmap != nullptr && t < 128) selmap[bh * 128 + t] = 0u;
    if (t == 0) { sPrefix = 0u; sMask = 0u; sK = UU; outCount = 0; eqCount = 0; }
    __syncthreads();

    for (int pass = 0; pass < 4; ++pass) {
        int shift = 24 - pass * 8;
        if (t < 256) hist[t] = 0u;
        __syncthreads();
        unsigned prefix = sPrefix, mask = sMask;
        for (int i = t; i < LL; i += 1024) {
            unsigned k = keys[i];
            if ((k & mask) == prefix)
                atomicAdd(&hist[(k >> shift) & 0xFFu], 1u);
        }
        __syncthreads();
        if (t < 256) scanbuf[t] = hist[t];
        __syncthreads();
        // suffix-sum: scanbuf[b] = count of keys with digit >= b (in subset)
        for (int off = 1; off < 256; off <<= 1) {
            unsigned v = 0u;
            if (t < 256 && t + off < 256) v = scanbuf[t + off];
            __syncthreads();
            if (t < 256) scanbuf[t] += v;
            __syncthreads();
        }
        if (t < 256) {
            unsigned k = sK;
            unsigned geq = scanbuf[t];
            unsigned gt = (t < 255) ? scanbuf[t + 1] : 0u;
            if (gt < k && geq >= k) sBin = (unsigned)t;
        }
        __syncthreads();
        if (t == 0) {
            unsigned b = sBin;
            unsigned gt = (b < 255u) ? scanbuf[b + 1] : 0u;
            sK -= gt;
            sPrefix |= (b << shift);
            sMask |= (0xFFu << shift);
        }
        __syncthreads();
    }
    unsigned T = sPrefix;
    int kEq = (int)sK;

    for (int i = t; i < LL; i += 1024) {
        unsigned k = keys[i];
        if (k > T) {
            int slot = atomicAdd(&outCount, 1);
            Mtop[bh * UU + slot] = i;
        } else if (k == T) {
            int e = atomicAdd(&eqCount, 1);
            if (e < 64) eqIdx[e] = i;
        }
    }
    __syncthreads();

    if (t == 0) {
        int base = outCount; // == UU - kEq
        int ec = eqCount;
        if (ec <= 64) {
            for (int s = 0; s < UU; ++s) { // s < kEq, bounded loop for compiler
                if (s >= kEq) break;
                int bi = -1, bv = LL + 2;
                for (int j = 0; j < ec; ++j) {
                    int v = eqIdx[j];
                    if (v < bv) { bv = v; bi = j; }
                }
                Mtop[bh * UU + base + s] = bv;
                eqIdx[bi] = LL + 2;
            }
        } else {
            // paranoid fallback (massive duplicate values): serial lowest-index
            int got = 0;
            for (int i = 0; i < LL && got < kEq; ++i)
                if (keys[i] == T) { Mtop[bh * UU + base + got] = i; ++got; }
        }
    }
    __syncthreads();
    if (selmap != nullptr && t < UU) {
        int qi = Mtop[bh * UU + t];
        atomicOr(&selmap[bh * 128 + (qi >> 5)], 1u << (qi & 31));
    }
}

// ---------------- Kernel 3: per-tile RAW sums of V over l (for cumsum) ---------
__global__ __launch_bounds__(256) void k_tilesum(
        const float* __restrict__ V, float* __restrict__ tsum) {
    int blk = blockIdx.x; // ((b*HH+h)*NTILES + tile)
    int tile = blk % NTILES;
    int bh = blk / NTILES;
    int h = bh % HH, b = bh / HH;
    int d = threadIdx.x & 63, g = threadIdx.x >> 6; // g in 0..3
    const int CH = TILE / 4;                        // 32
    int l0 = tile * TILE + g * CH;
    float acc = 0.f;
    for (int i = 0; i < CH; ++i) acc += V[qkv_idx(b, l0 + i, h, d)];
    __shared__ float red[4][DD];
    red[g][d] = acc;
    __syncthreads();
    if (g == 0) tsum[blk * DD + d] = red[0][d] + red[1][d] + red[2][d] + red[3][d];
}

// ---------------- Kernel 4: cumsum(V) -> out, with in-block tile prefix --------
// Computes the exclusive prefix over raw tile sums itself (parallel: 4
// threads per d-column, coalesced 256B loads). Skips rows flagged in selmap
// (those are written by k_attn_combine, which runs BEFORE this kernel).
__global__ __launch_bounds__(256) void k_cumsum(
        const float* __restrict__ V, const float* __restrict__ tsum,
        const unsigned* __restrict__ selmap, float* __restrict__ out) {
    int blk = blockIdx.x;
    int tile = blk % NTILES;
    int bh = blk / NTILES;
    int h = bh % HH, b = bh / HH;
    int t = threadIdx.x;
    int d = t & 63, g = t >> 6;
    const int CH = TILE / 4;
    int l0 = tile * TILE + g * CH;

    __shared__ float red[4][DD];
    __shared__ float pre2[4][DD];
    float acc = 0.f;
    for (int i = 0; i < CH; ++i) acc += V[qkv_idx(b, l0 + i, h, d)];
    red[g][d] = acc;
    float p = 0.f;
    for (int tt = g; tt < tile; tt += 4)
        p += tsum[(bh * NTILES + tt) * DD + d];
    pre2[g][d] = p;
    __syncthreads();

    float off = pre2[0][d] + pre2[1][d] + pre2[2][d] + pre2[3][d];
    for (int gg = 0; gg < g; ++gg) off += red[gg][d];

    // rows l0..l0+31 share one bitmap word: l>>5 == tile*4+g
    unsigned selw = (selmap != nullptr) ? selmap[bh * 128 + (l0 >> 5)] : 0u;

    float run = off;
    for (int i = 0; i < CH; ++i) {
        run += V[qkv_idx(b, l0 + i, h, d)];
        if (!((selw >> i) & 1u))
            out[qkv_idx(b, l0 + i, h, d)] = run;
    }
}

// ---------------- Kernel 5a: split-K flash attention partials ------------------
__global__ __launch_bounds__(256) void k_attn_partial(
        const float* __restrict__ Q, const float* __restrict__ K,
        const float* __restrict__ V, const int* __restrict__ Mtop,
        float* __restrict__ mPart, float* __restrict__ lPart,
        float* __restrict__ Op) {
    int blk = blockIdx.x;      // bh * NC + c
    int c = blk % NC;
    int bh = blk / NC;
    int h = bh % HH, b = bh / HH;
    int k0 = c * CK;
    int t = threadIdx.x;

    __shared__ float Qs[48 * KSTR];   // 13056 B (rows 45..47 zeroed)
    __shared__ float Ks[CK * KSTR];   // 17408 B (reused for V in PV phase)
    __shared__ float Ss[UU * SSTR];   // 12240 B

    const size_t rowStride = (size_t)HH * DD; // 512 floats
    const float* Qbh = Q + (size_t)(b * LL * HH + h) * DD;
    const float* Kbh = K + (size_t)(b * LL * HH + h) * DD;
    const float* Vbh = V + (size_t)(b * LL * HH + h) * DD;

    for (int p = t; p < 48 * DD; p += 256) {
        int u = p >> 6, d = p & 63;
        float v = 0.f;
        if (u < UU) {
            int qi = Mtop[bh * UU + u];
            v = Qbh[(size_t)qi * rowStride + d] * 0.125f;
        }
        Qs[u * KSTR + d] = v;
    }
    for (int p = t; p < CK * 16; p += 256) {
        int row = p >> 4, i = p & 15;
        *(float4*)&Ks[row * KSTR + i * 4] =
            *(const float4*)&Kbh[(size_t)(k0 + row) * rowStride + i * 4];
    }
    __syncthreads();

    // --- scores GEMM: thread tile 3u x 4k ---
    int kq = t & 15, uq = t >> 4;
    int u0 = uq * 3;
    float acc[3][4];
#pragma unroll
    for (int i = 0; i < 3; ++i)
#pragma unroll
        for (int j = 0; j < 4; ++j) acc[i][j] = 0.f;

#pragma unroll 4
    for (int dd = 0; dd < 16; ++dd) {
        float4 qf[3];
#pragma unroll
        for (int i = 0; i < 3; ++i)
            qf[i] = *(const float4*)&Qs[(u0 + i) * KSTR + dd * 4];
        float4 kf[4];
#pragma unroll
        for (int j = 0; j < 4; ++j)
            kf[j] = *(const float4*)&Ks[(kq + 16 * j) * KSTR + dd * 4];
#pragma unroll
        for (int i = 0; i < 3; ++i)
#pragma unroll
            for (int j = 0; j < 4; ++j) {
                acc[i][j] = fmaf(qf[i].x, kf[j].x, acc[i][j]);
                acc[i][j] = fmaf(qf[i].y, kf[j].y, acc[i][j]);
                acc[i][j] = fmaf(qf[i].z, kf[j].z, acc[i][j]);
                acc[i][j] = fmaf(qf[i].w, kf[j].w, acc[i][j]);
            }
    }
#pragma unroll
    for (int i = 0; i < 3; ++i) {
        int u = u0 + i;
        if (u < UU)
#pragma unroll
            for (int j = 0; j < 4; ++j) Ss[u * SSTR + kq + 16 * j] = acc[i][j];
    }
    __syncthreads();

    // stage V chunk into the K buffer (no one reads Ks until next barrier)
    for (int p = t; p < CK * 16; p += 256) {
        int row = p >> 4, i = p & 15;
        *(float4*)&Ks[row * KSTR + i * 4] =
            *(const float4*)&Vbh[(size_t)(k0 + row) * rowStride + i * 4];
    }

    // --- chunk-local softmax: 4 threads per u ---
    if (t < UU * 4) {
        int u = t >> 2, qq = t & 3;
        float mloc = -INFINITY;
        for (int j = 0; j < CK / 4; ++j)
            mloc = fmaxf(mloc, Ss[u * SSTR + qq + 4 * j]);
        mloc = fmaxf(mloc, __shfl_xor(mloc, 1, 64));
        mloc = fmaxf(mloc, __shfl_xor(mloc, 2, 64));
        float lloc = 0.f;
        for (int j = 0; j < CK / 4; ++j) {
            int kk = qq + 4 * j;
            float e = __expf(Ss[u * SSTR + kk] - mloc);
            Ss[u * SSTR + kk] = e;
            lloc += e;
        }
        lloc += __shfl_xor(lloc, 1, 64);
        lloc += __shfl_xor(lloc, 2, 64);
        if (qq == 0) {
            mPart[(bh * NC + c) * UU + u] = mloc;
            lPart[(bh * NC + c) * UU + u] = lloc;
        }
    }
    __syncthreads();

    // --- PV GEMM: thread tile 3u x 4d ---
    int dq = t & 15;
    int d0 = dq * 4;
    if (u0 < UU) { // uq==15 idle
        float4 o[3];
#pragma unroll
        for (int i = 0; i < 3; ++i) o[i] = make_float4(0.f, 0.f, 0.f, 0.f);
#pragma unroll 4
        for (int kc = 0; kc < CK / 4; ++kc) {
            float4 vk[4];
#pragma unroll
            for (int jj = 0; jj < 4; ++jj)
                vk[jj] = *(const float4*)&Ks[(4 * kc + jj) * KSTR + d0];
#pragma unroll
            for (int i = 0; i < 3; ++i) {
                float4 pf = *(const float4*)&Ss[(u0 + i) * SSTR + 4 * kc];
                o[i].x = fmaf(pf.x, vk[0].x, o[i].x);
                o[i].y = fmaf(pf.x, vk[0].y, o[i].y);
                o[i].z = fmaf(pf.x, vk[0].z, o[i].z);
                o[i].w = fmaf(pf.x, vk[0].w, o[i].w);
                o[i].x = fmaf(pf.y, vk[1].x, o[i].x);
                o[i].y = fmaf(pf.y, vk[1].y, o[i].y);
                o[i].z = fmaf(pf.y, vk[1].z, o[i].z);
                o[i].w = fmaf(pf.y, vk[1].w, o[i].w);
                o[i].x = fmaf(pf.z, vk[2].x, o[i].x);
                o[i].y = fmaf(pf.z, vk[2].y, o[i].y);
                o[i].z = fmaf(pf.z, vk[2].z, o[i].z);
                o[i].w = fmaf(pf.z, vk[2].w, o[i].w);
                o[i].x = fmaf(pf.w, vk[3].x, o[i].x);
                o[i].y = fmaf(pf.w, vk[3].y, o[i].y);
                o[i].z = fmaf(pf.w, vk[3].z, o[i].z);
                o[i].w = fmaf(pf.w, vk[3].w, o[i].w);
            }
        }
#pragma unroll
        for (int i = 0; i < 3; ++i) {
            int u = u0 + i;
            *(float4*)&Op[((size_t)(bh * NC + c) * UU + u) * DD + d0] = o[i];
        }
    }
}

// ---------------- Kernel 5b: flash combine across chunks, scatter --------------
// Runs BEFORE k_cumsum; cumsum skips these rows via selmap.
__global__ void k_attn_combine(
        const int* __restrict__ Mtop, const float* __restrict__ mPart,
        const float* __restrict__ lPart, const float* __restrict__ Op,
        float* __restrict__ out) {
    int blk = blockIdx.x; // bh*UU + u
    int u = blk % UU;
    int bh = blk / UU;
    int h = bh % HH, b = bh / HH;
    int d = threadIdx.x;  // 64
    float gm = -INFINITY;
    for (int c = 0; c < NC; ++c)
        gm = fmaxf(gm, mPart[(bh * NC + c) * UU + u]);
    float denom = 0.f, acc = 0.f;
    for (int c = 0; c < NC; ++c) {
        int pi = (bh * NC + c) * UU + u;
        float w = __expf(mPart[pi] - gm);
        denom = fmaf(lPart[pi], w, denom);
        acc = fmaf(w, Op[(size_t)pi * DD + d], acc);
    }
    int qi = Mtop[bh * UU + u];
    out[qkv_idx(b, qi, h, d)] = acc / denom;
}

// ---------------- Fallback: monolithic per-(bh,u) attention --------------------
__global__ __launch_bounds__(256) void k_attn_mono(
        const float* __restrict__ Q, const float* __restrict__ K,
        const float* __restrict__ V, const int* __restrict__ Mtop,
        float* __restrict__ out) {
    int blk = blockIdx.x; // bh*UU + u
    int u = blk % UU;
    int bh = blk / UU;
    int h = bh % HH, b = bh / HH;
    int qi = Mtop[bh * UU + u];
    int t = threadIdx.x;

    __shared__ float scores[LL];
    __shared__ float red[256];

    const float4* qp = (const float4*)(Q + qkv_idx(b, qi, h, 0));
    float4 qreg[16];
#pragma unroll
    for (int i = 0; i < 16; ++i) {
        float4 v = qp[i];
        v.x *= 0.125f; v.y *= 0.125f; v.z *= 0.125f; v.w *= 0.125f;
        qreg[i] = v;
    }

    float lmax = -INFINITY;
    for (int k = t; k < LL; k += 256) {
        const float4* kr = (const float4*)(K + qkv_idx(b, k, h, 0));
        float dot = 0.f;
#pragma unroll
        for (int i = 0; i < 16; ++i) {
            float4 kk = kr[i];
            dot = fmaf(qreg[i].x, kk.x, dot);
            dot = fmaf(qreg[i].y, kk.y, dot);
            dot = fmaf(qreg[i].z, kk.z, dot);
            dot = fmaf(qreg[i].w, kk.w, dot);
        }
        scores[k] = dot;
        lmax = fmaxf(lmax, dot);
    }
    red[t] = lmax;
    __syncthreads();
    for (int off = 128; off >= 1; off >>= 1) {
        if (t < off) red[t] = fmaxf(red[t], red[t + off]);
        __syncthreads();
    }
    float smax = red[0];
    __syncthreads();

    float lsum = 0.f;
    for (int k = t; k < LL; k += 256) {
        float e = __expf(scores[k] - smax);
        scores[k] = e;
        lsum += e;
    }
    red[t] = lsum;
    __syncthreads();
    for (int off = 128; off >= 1; off >>= 1) {
        if (t < off) red[t] += red[t + off];
        __syncthreads();
    }
    float denom = red[0];
    __syncthreads();

    int d = t & 63, g = t >> 6;
    const float4* sc4 = (const float4*)scores;
    float acc = 0.f;
    for (int kb = g; kb < LL / 4; kb += 4) {
        float4 s4 = sc4[kb];
        int kk0 = kb * 4;
        acc = fmaf(s4.x, V[qkv_idx(b, kk0 + 0, h, d)], acc);
        acc = fmaf(s4.y, V[qkv_idx(b, kk0 + 1, h, d)], acc);
        acc = fmaf(s4.z, V[qkv_idx(b, kk0 + 2, h, d)], acc);
        acc = fmaf(s4.w, V[qkv_idx(b, kk0 + 3, h, d)], acc);
    }
    red[t] = acc;
    __syncthreads();
    if (g == 0) {
        float s = red[d] + red[64 + d] + red[128 + d] + red[192 + d];
        out[qkv_idx(b, qi, h, d)] = s / denom;
    }
}

extern "C" void kernel_launch(void* const* d_in, const int* in_sizes, int n_in,
                              void* d_out, int out_size, void* d_ws, size_t ws_size,
                              hipStream_t stream) {
    const float* Q = (const float*)d_in[0];
    const float* K = (const float*)d_in[1];
    const float* V = (const float*)d_in[2];
    const int* idx = (const int*)d_in[3];
    float* out = (float*)d_out;

    float* ws = (float*)d_ws;

    // workspace layout (floats)
    const size_t M_off = 0;                           // 65536
    const size_t tsum_off = 65536;                    // 32768
    const size_t mP_off = 98304;                      // 16*64*45 = 46080
    const size_t lP_off = 144384;                     // 46080
    const size_t top_off = 190464;                    // 720 ints (reserve 1024)
    const size_t sel_off = 191488;                    // 16*128 uints (2048)
    const size_t Op_off = 193536;                     // 16*64*45*64 = 2949120
    const size_t need = (Op_off + (size_t)BB * HH * NC * UU * DD) * 4;

    float* M = ws + M_off;
    float* tsum = ws + tsum_off;

    if (ws_size >= need) {
        float* mPart = ws + mP_off;
        float* lPart = ws + lP_off;
        int* Mtop = (int*)(ws + top_off);
        unsigned* selmap = (unsigned*)(ws + sel_off);
        float* Op = ws + Op_off;

        k_computeM<<<BB * HH * LL / 4, 256, 0, stream>>>(Q, K, idx, M);
        k_topk<<<BB * HH, 1024, 0, stream>>>(M, Mtop, selmap);
        k_attn_partial<<<BB * HH * NC, 256, 0, stream>>>(Q, K, V, Mtop,
                                                         mPart, lPart, Op);
        k_tilesum<<<BB * HH * NTILES, 256, 0, stream>>>(V, tsum);
        k_attn_combine<<<BB * HH * UU, 64, 0, stream>>>(Mtop, mPart, lPart,
                                                        Op, out);
        k_cumsum<<<BB * HH * NTILES, 256, 0, stream>>>(V, tsum, selmap, out);
    } else {
        // compact fallback layout
        int* Mtop = (int*)(ws + 65536);
        float* tsum2 = ws + 65536 + 1024;
        k_computeM<<<BB * HH * LL / 4, 256, 0, stream>>>(Q, K, idx, M);
        k_topk<<<BB * HH, 1024, 0, stream>>>(M, Mtop, (unsigned*)nullptr);
        k_tilesum<<<BB * HH * NTILES, 256, 0, stream>>>(V, tsum2);
        k_cumsum<<<BB * HH * NTILES, 256, 0, stream>>>(V, tsum2,
                                                       (const unsigned*)nullptr,
                                                       out);
        k_attn_mono<<<BB * HH * UU, 256, 0, stream>>>(Q, K, V, Mtop, out);
    }
}

// Round 7
// 187.401 us; speedup vs baseline: 1.1967x; 1.1122x over previous
//
#include <hip/hip_runtime.h>
#include <math.h>

#define BB 2
#define LL 4096
#define HH 8
#define DD 64
#define UU 45
#define TILE 128
#define NTILES (LL / TILE) // 32

// split-K attention config
#define NC 64              // key chunks
#define CK (LL / NC)       // 64 keys per chunk
#define KSTR 68            // padded LDS row stride (floats) for K/V/Q tiles
#define SSTR 68            // padded LDS row stride for scores (CK=64 + 4)

#define NB_CM (BB * HH * LL / 4)   // 16384 computeM blocks (4 waves each)
#define NB_TS (BB * HH * NTILES)   // 512 tilesum blocks
#define NB_CU (BB * HH * NTILES)   // 512 cumsum blocks
#define NB_CO (BB * HH * UU / 4)   // 180 combine blocks (4 u's per block)

__device__ __forceinline__ int qkv_idx(int b, int l, int h, int d) {
    return ((b * LL + l) * HH + h) * DD + d;
}

// DPP all-reduce helper: v += rotate-within-16-lane-row(v, N). VALU pipe only.
template <int CTRL>
__device__ __forceinline__ float dpp_add(float v) {
    int x = __builtin_amdgcn_update_dpp(0, __float_as_int(v), CTRL, 0xF, 0xF,
                                        true);
    return v + __int_as_float(x);
}

// ---------------- Kernel A: sparsity metric M[b,h,q]  ∥  V tile sums -----------
// computeM: one wave per query; 16 lanes per sampled K row (4 contiguous 256B
// runs per load instr -- segment-optimal). Round-6 PMC showed latency-bound
// (VALU 42%, HBM 19%, VGPR=32 -> ~2 loads in flight). Round-7: preload all 12
// sample indices (breaks idx->Kaddr chain), then 2 batches of 6 float4 K loads
// in flight (ILP 6). tilesum blocks appended to the same grid -- independent
// work that fills the memory pipe while computeM waves stall on latency.
__global__ __launch_bounds__(256) void k_computeM_tilesum(
        const float* __restrict__ Q, const float* __restrict__ K,
        const int* __restrict__ idx, const float* __restrict__ V,
        float* __restrict__ M, float* __restrict__ tsum) {
    if (blockIdx.x >= NB_CM) {
        // ---- tilesum branch ----
        int blk = blockIdx.x - NB_CM;  // ((b*HH+h)*NTILES + tile)
        int tile = blk % NTILES;
        int bh = blk / NTILES;
        int h = bh % HH, b = bh / HH;
        int d = threadIdx.x & 63, g = threadIdx.x >> 6; // g in 0..3
        const int CH = TILE / 4;                        // 32
        int l0 = tile * TILE + g * CH;
        float acc = 0.f;
        for (int i = 0; i < CH; ++i) acc += V[qkv_idx(b, l0 + i, h, d)];
        __shared__ float red[4][DD];
        red[g][d] = acc;
        __syncthreads();
        if (g == 0)
            tsum[blk * DD + d] =
                red[0][d] + red[1][d] + red[2][d] + red[3][d];
        return;
    }
    // ---- computeM branch ----
    int w = (blockIdx.x * blockDim.x + threadIdx.x) >> 6; // global wave id
    int lane = threadIdx.x & 63;
    int q = w % LL;
    int bh = w / LL;            // b*HH + h
    int h = bh % HH, b = bh / HH;

    const float* Kbh = K + (size_t)(b * LL * HH + h) * DD;
    const size_t rowStride = (size_t)HH * DD; // 512 floats between key rows

    int r = lane >> 4;    // which of 4 rows this lane helps load (DPP row id)
    int c16 = lane & 15;  // position within 16-lane row group

    // lane covers floats c16*4 .. c16*4+3 of both Q row and sampled K rows
    const float4 qf = *(const float4*)(Q + qkv_idx(b, q, h, c16 * 4));
    const int* idxRow = idx + q * UU;

    // preload ALL sample indices first: removes the idx-load from the
    // K-address dependency chain so K loads can batch.
    int ks[12];
#pragma unroll
    for (int g = 0; g < 12; ++g) {
        int s = g * 4 + r;
        ks[g] = idxRow[s < UU ? s : 0];  // clamped (row-end OOB guard)
    }

    float mval = -INFINITY, sval = 0.f;
#pragma unroll
    for (int half = 0; half < 2; ++half) {
        // issue 6 independent K-row loads (24 VGPRs in flight)
        float4 kk[6];
#pragma unroll
        for (int j = 0; j < 6; ++j)
            kk[j] = ((const float4*)(Kbh +
                        (size_t)ks[half * 6 + j] * rowStride))[c16];
#pragma unroll
        for (int j = 0; j < 6; ++j) {
            int g = half * 6 + j;
            float part = fmaf(kk[j].x, qf.x,
                         fmaf(kk[j].y, qf.y,
                         fmaf(kk[j].z, qf.z, kk[j].w * qf.w)));
            // all-reduce across the 16-lane row: DPP rotations (VALU pipe)
            part = dpp_add<0x128>(part); // row_ror:8
            part = dpp_add<0x124>(part); // row_ror:4
            part = dpp_add<0x122>(part); // row_ror:2
            part = dpp_add<0x121>(part); // row_ror:1
            int s = g * 4 + r;
            if (s < UU) { mval = fmaxf(mval, part); sval += part; }
        }
    }
    // combine the 4 row groups (lanes differing in bits 4,5)
    mval = fmaxf(mval, __shfl_xor(mval, 16, 64));
    sval += __shfl_xor(sval, 16, 64);
    mval = fmaxf(mval, __shfl_xor(mval, 32, 64));
    sval += __shfl_xor(sval, 32, 64);
    if (lane == 0) M[bh * LL + q] = mval - sval * (1.0f / LL);
}

// ---------------- Kernel 2: top-45 via 4-pass radix select ---------------------
// One block of 1024 threads per (b,h). Monotonic key transform, 8-bit MSD
// radix passes locate the exact 45th-largest key; collection pass emits all
// strictly-greater indices plus the lowest-index ties. Also emits a 4096-bit
// selection bitmap (selmap) so cumsum can skip rows that combine writes.
__global__ __launch_bounds__(1024) void k_topk(
        const float* __restrict__ M, int* __restrict__ Mtop,
        unsigned* __restrict__ selmap) {
    int bh = blockIdx.x;
    int t = threadIdx.x;
    __shared__ unsigned keys[LL];      // 16 KB
    __shared__ unsigned hist[256];
    __shared__ unsigned scanbuf[256];
    __shared__ unsigned sPrefix, sMask, sK, sBin;
    __shared__ int outCount, eqCount;
    __shared__ int eqIdx[64];

    for (int i = t; i < LL; i += 1024) {
        unsigned u = __float_as_uint(M[bh * LL + i]);
        keys[i] = (u & 0x80000000u) ? ~u : (u | 0x80000000u);
    }
    if (selmap != nullptr && t < 128) selmap[bh * 128 + t] = 0u;
    if (t == 0) { sPrefix = 0u; sMask = 0u; sK = UU; outCount = 0; eqCount = 0; }
    __syncthreads();

    for (int pass = 0; pass < 4; ++pass) {
        int shift = 24 - pass * 8;
        if (t < 256) hist[t] = 0u;
        __syncthreads();
        unsigned prefix = sPrefix, mask = sMask;
        for (int i = t; i < LL; i += 1024) {
            unsigned k = keys[i];
            if ((k & mask) == prefix)
                atomicAdd(&hist[(k >> shift) & 0xFFu], 1u);
        }
        __syncthreads();
        if (t < 256) scanbuf[t] = hist[t];
        __syncthreads();
        // suffix-sum: scanbuf[b] = count of keys with digit >= b (in subset)
        for (int off = 1; off < 256; off <<= 1) {
            unsigned v = 0u;
            if (t < 256 && t + off < 256) v = scanbuf[t + off];
            __syncthreads();
            if (t < 256) scanbuf[t] += v;
            __syncthreads();
        }
        if (t < 256) {
            unsigned k = sK;
            unsigned geq = scanbuf[t];
            unsigned gt = (t < 255) ? scanbuf[t + 1] : 0u;
            if (gt < k && geq >= k) sBin = (unsigned)t;
        }
        __syncthreads();
        if (t == 0) {
            unsigned b = sBin;
            unsigned gt = (b < 255u) ? scanbuf[b + 1] : 0u;
            sK -= gt;
            sPrefix |= (b << shift);
            sMask |= (0xFFu << shift);
        }
        __syncthreads();
    }
    unsigned T = sPrefix;
    int kEq = (int)sK;

    for (int i = t; i < LL; i += 1024) {
        unsigned k = keys[i];
        if (k > T) {
            int slot = atomicAdd(&outCount, 1);
            Mtop[bh * UU + slot] = i;
        } else if (k == T) {
            int e = atomicAdd(&eqCount, 1);
            if (e < 64) eqIdx[e] = i;
        }
    }
    __syncthreads();

    if (t == 0) {
        int base = outCount; // == UU - kEq
        int ec = eqCount;
        if (ec <= 64) {
            for (int s = 0; s < UU; ++s) { // s < kEq, bounded loop for compiler
                if (s >= kEq) break;
                int bi = -1, bv = LL + 2;
                for (int j = 0; j < ec; ++j) {
                    int v = eqIdx[j];
                    if (v < bv) { bv = v; bi = j; }
                }
                Mtop[bh * UU + base + s] = bv;
                eqIdx[bi] = LL + 2;
            }
        } else {
            // paranoid fallback (massive duplicate values): serial lowest-index
            int got = 0;
            for (int i = 0; i < LL && got < kEq; ++i)
                if (keys[i] == T) { Mtop[bh * UU + base + got] = i; ++got; }
        }
    }
    __syncthreads();
    if (selmap != nullptr && t < UU) {
        int qi = Mtop[bh * UU + t];
        atomicOr(&selmap[bh * 128 + (qi >> 5)], 1u << (qi & 31));
    }
}

// ---------------- Kernel 5a: split-K flash attention partials ------------------
__global__ __launch_bounds__(256) void k_attn_partial(
        const float* __restrict__ Q, const float* __restrict__ K,
        const float* __restrict__ V, const int* __restrict__ Mtop,
        float* __restrict__ mPart, float* __restrict__ lPart,
        float* __restrict__ Op) {
    int blk = blockIdx.x;      // bh * NC + c
    int c = blk % NC;
    int bh = blk / NC;
    int h = bh % HH, b = bh / HH;
    int k0 = c * CK;
    int t = threadIdx.x;

    __shared__ float Qs[48 * KSTR];   // 13056 B (rows 45..47 zeroed)
    __shared__ float Ks[CK * KSTR];   // 17408 B (reused for V in PV phase)
    __shared__ float Ss[UU * SSTR];   // 12240 B

    const size_t rowStride = (size_t)HH * DD; // 512 floats
    const float* Qbh = Q + (size_t)(b * LL * HH + h) * DD;
    const float* Kbh = K + (size_t)(b * LL * HH + h) * DD;
    const float* Vbh = V + (size_t)(b * LL * HH + h) * DD;

    for (int p = t; p < 48 * DD; p += 256) {
        int u = p >> 6, d = p & 63;
        float v = 0.f;
        if (u < UU) {
            int qi = Mtop[bh * UU + u];
            v = Qbh[(size_t)qi * rowStride + d] * 0.125f;
        }
        Qs[u * KSTR + d] = v;
    }
    for (int p = t; p < CK * 16; p += 256) {
        int row = p >> 4, i = p & 15;
        *(float4*)&Ks[row * KSTR + i * 4] =
            *(const float4*)&Kbh[(size_t)(k0 + row) * rowStride + i * 4];
    }
    __syncthreads();

    // --- scores GEMM: thread tile 3u x 4k ---
    int kq = t & 15, uq = t >> 4;
    int u0 = uq * 3;
    float acc[3][4];
#pragma unroll
    for (int i = 0; i < 3; ++i)
#pragma unroll
        for (int j = 0; j < 4; ++j) acc[i][j] = 0.f;

#pragma unroll 4
    for (int dd = 0; dd < 16; ++dd) {
        float4 qf[3];
#pragma unroll
        for (int i = 0; i < 3; ++i)
            qf[i] = *(const float4*)&Qs[(u0 + i) * KSTR + dd * 4];
        float4 kf[4];
#pragma unroll
        for (int j = 0; j < 4; ++j)
            kf[j] = *(const float4*)&Ks[(kq + 16 * j) * KSTR + dd * 4];
#pragma unroll
        for (int i = 0; i < 3; ++i)
#pragma unroll
            for (int j = 0; j < 4; ++j) {
                acc[i][j] = fmaf(qf[i].x, kf[j].x, acc[i][j]);
                acc[i][j] = fmaf(qf[i].y, kf[j].y, acc[i][j]);
                acc[i][j] = fmaf(qf[i].z, kf[j].z, acc[i][j]);
                acc[i][j] = fmaf(qf[i].w, kf[j].w, acc[i][j]);
            }
    }
#pragma unroll
    for (int i = 0; i < 3; ++i) {
        int u = u0 + i;
        if (u < UU)
#pragma unroll
            for (int j = 0; j < 4; ++j) Ss[u * SSTR + kq + 16 * j] = acc[i][j];
    }
    __syncthreads();

    // stage V chunk into the K buffer (no one reads Ks until next barrier)
    for (int p = t; p < CK * 16; p += 256) {
        int row = p >> 4, i = p & 15;
        *(float4*)&Ks[row * KSTR + i * 4] =
            *(const float4*)&Vbh[(size_t)(k0 + row) * rowStride + i * 4];
    }

    // --- chunk-local softmax: 4 threads per u ---
    if (t < UU * 4) {
        int u = t >> 2, qq = t & 3;
        float mloc = -INFINITY;
        for (int j = 0; j < CK / 4; ++j)
            mloc = fmaxf(mloc, Ss[u * SSTR + qq + 4 * j]);
        mloc = fmaxf(mloc, __shfl_xor(mloc, 1, 64));
        mloc = fmaxf(mloc, __shfl_xor(mloc, 2, 64));
        float lloc = 0.f;
        for (int j = 0; j < CK / 4; ++j) {
            int kk = qq + 4 * j;
            float e = __expf(Ss[u * SSTR + kk] - mloc);
            Ss[u * SSTR + kk] = e;
            lloc += e;
        }
        lloc += __shfl_xor(lloc, 1, 64);
        lloc += __shfl_xor(lloc, 2, 64);
        if (qq == 0) {
            mPart[(bh * NC + c) * UU + u] = mloc;
            lPart[(bh * NC + c) * UU + u] = lloc;
        }
    }
    __syncthreads();

    // --- PV GEMM: thread tile 3u x 4d ---
    int dq = t & 15;
    int d0 = dq * 4;
    if (u0 < UU) { // uq==15 idle
        float4 o[3];
#pragma unroll
        for (int i = 0; i < 3; ++i) o[i] = make_float4(0.f, 0.f, 0.f, 0.f);
#pragma unroll 4
        for (int kc = 0; kc < CK / 4; ++kc) {
            float4 vk[4];
#pragma unroll
            for (int jj = 0; jj < 4; ++jj)
                vk[jj] = *(const float4*)&Ks[(4 * kc + jj) * KSTR + d0];
#pragma unroll
            for (int i = 0; i < 3; ++i) {
                float4 pf = *(const float4*)&Ss[(u0 + i) * SSTR + 4 * kc];
                o[i].x = fmaf(pf.x, vk[0].x, o[i].x);
                o[i].y = fmaf(pf.x, vk[0].y, o[i].y);
                o[i].z = fmaf(pf.x, vk[0].z, o[i].z);
                o[i].w = fmaf(pf.x, vk[0].w, o[i].w);
                o[i].x = fmaf(pf.y, vk[1].x, o[i].x);
                o[i].y = fmaf(pf.y, vk[1].y, o[i].y);
                o[i].z = fmaf(pf.y, vk[1].z, o[i].z);
                o[i].w = fmaf(pf.y, vk[1].w, o[i].w);
                o[i].x = fmaf(pf.z, vk[2].x, o[i].x);
                o[i].y = fmaf(pf.z, vk[2].y, o[i].y);
                o[i].z = fmaf(pf.z, vk[2].z, o[i].z);
                o[i].w = fmaf(pf.z, vk[2].w, o[i].w);
                o[i].x = fmaf(pf.w, vk[3].x, o[i].x);
                o[i].y = fmaf(pf.w, vk[3].y, o[i].y);
                o[i].z = fmaf(pf.w, vk[3].z, o[i].z);
                o[i].w = fmaf(pf.w, vk[3].w, o[i].w);
            }
        }
#pragma unroll
        for (int i = 0; i < 3; ++i) {
            int u = u0 + i;
            *(float4*)&Op[((size_t)(bh * NC + c) * UU + u) * DD + d0] = o[i];
        }
    }
}

// ---------------- Kernel B: cumsum(V)  ∥  flash combine (disjoint rows) --------
// cumsum writes all rows NOT in selmap; combine writes exactly the selmap rows
// -- disjoint output sets, so the two halves can share one launch with no
// ordering constraint. cumsum computes its tile prefix in-block (4 threads
// per d-column over raw tile sums).
__global__ __launch_bounds__(256) void k_cumsum_combine(
        const float* __restrict__ V, const float* __restrict__ tsum,
        const unsigned* __restrict__ selmap, const int* __restrict__ Mtop,
        const float* __restrict__ mPart, const float* __restrict__ lPart,
        const float* __restrict__ Op, float* __restrict__ out) {
    int t = threadIdx.x;
    if (blockIdx.x >= NB_CU) {
        // ---- combine branch: 4 u-slots per block, 64 threads each ----
        int u4 = (blockIdx.x - NB_CU) * 4 + (t >> 6); // 0..719
        int u = u4 % UU;
        int bh = u4 / UU;
        int h = bh % HH, b = bh / HH;
        int d = t & 63;
        float gm = -INFINITY;
        for (int c = 0; c < NC; ++c)
            gm = fmaxf(gm, mPart[(bh * NC + c) * UU + u]);
        float denom = 0.f, acc = 0.f;
        for (int c = 0; c < NC; ++c) {
            int pi = (bh * NC + c) * UU + u;
            float w = __expf(mPart[pi] - gm);
            denom = fmaf(lPart[pi], w, denom);
            acc = fmaf(w, Op[(size_t)pi * DD + d], acc);
        }
        int qi = Mtop[bh * UU + u];
        out[qkv_idx(b, qi, h, d)] = acc / denom;
        return;
    }
    // ---- cumsum branch ----
    int blk = blockIdx.x;
    int tile = blk % NTILES;
    int bh = blk / NTILES;
    int h = bh % HH, b = bh / HH;
    int d = t & 63, g = t >> 6;
    const int CH = TILE / 4;
    int l0 = tile * TILE + g * CH;

    __shared__ float red[4][DD];
    __shared__ float pre2[4][DD];
    float acc = 0.f;
    for (int i = 0; i < CH; ++i) acc += V[qkv_idx(b, l0 + i, h, d)];
    red[g][d] = acc;
    float p = 0.f;
    for (int tt = g; tt < tile; tt += 4)
        p += tsum[(bh * NTILES + tt) * DD + d];
    pre2[g][d] = p;
    __syncthreads();

    float off = pre2[0][d] + pre2[1][d] + pre2[2][d] + pre2[3][d];
    for (int gg = 0; gg < g; ++gg) off += red[gg][d];

    // rows l0..l0+31 share one bitmap word: l>>5 == tile*4+g
    unsigned selw = selmap[bh * 128 + (l0 >> 5)];

    float run = off;
    for (int i = 0; i < CH; ++i) {
        run += V[qkv_idx(b, l0 + i, h, d)];
        if (!((selw >> i) & 1u))
            out[qkv_idx(b, l0 + i, h, d)] = run;
    }
}

// ---------------- Fallback-path kernels ----------------------------------------
__global__ __launch_bounds__(256) void k_cumsum_fb(
        const float* __restrict__ V, const float* __restrict__ tsum,
        float* __restrict__ out) {
    int blk = blockIdx.x;
    int tile = blk % NTILES;
    int bh = blk / NTILES;
    int h = bh % HH, b = bh / HH;
    int t = threadIdx.x;
    int d = t & 63, g = t >> 6;
    const int CH = TILE / 4;
    int l0 = tile * TILE + g * CH;

    __shared__ float red[4][DD];
    __shared__ float pre2[4][DD];
    float acc = 0.f;
    for (int i = 0; i < CH; ++i) acc += V[qkv_idx(b, l0 + i, h, d)];
    red[g][d] = acc;
    float p = 0.f;
    for (int tt = g; tt < tile; tt += 4)
        p += tsum[(bh * NTILES + tt) * DD + d];
    pre2[g][d] = p;
    __syncthreads();

    float off = pre2[0][d] + pre2[1][d] + pre2[2][d] + pre2[3][d];
    for (int gg = 0; gg < g; ++gg) off += red[gg][d];

    float run = off;
    for (int i = 0; i < CH; ++i) {
        run += V[qkv_idx(b, l0 + i, h, d)];
        out[qkv_idx(b, l0 + i, h, d)] = run;
    }
}

__global__ __launch_bounds__(256) void k_attn_mono(
        const float* __restrict__ Q, const float* __restrict__ K,
        const float* __restrict__ V, const int* __restrict__ Mtop,
        float* __restrict__ out) {
    int blk = blockIdx.x; // bh*UU + u
    int u = blk % UU;
    int bh = blk / UU;
    int h = bh % HH, b = bh / HH;
    int qi = Mtop[bh * UU + u];
    int t = threadIdx.x;

    __shared__ float scores[LL];
    __shared__ float red[256];

    const float4* qp = (const float4*)(Q + qkv_idx(b, qi, h, 0));
    float4 qreg[16];
#pragma unroll
    for (int i = 0; i < 16; ++i) {
        float4 v = qp[i];
        v.x *= 0.125f; v.y *= 0.125f; v.z *= 0.125f; v.w *= 0.125f;
        qreg[i] = v;
    }

    float lmax = -INFINITY;
    for (int k = t; k < LL; k += 256) {
        const float4* kr = (const float4*)(K + qkv_idx(b, k, h, 0));
        float dot = 0.f;
#pragma unroll
        for (int i = 0; i < 16; ++i) {
            float4 kk = kr[i];
            dot = fmaf(qreg[i].x, kk.x, dot);
            dot = fmaf(qreg[i].y, kk.y, dot);
            dot = fmaf(qreg[i].z, kk.z, dot);
            dot = fmaf(qreg[i].w, kk.w, dot);
        }
        scores[k] = dot;
        lmax = fmaxf(lmax, dot);
    }
    red[t] = lmax;
    __syncthreads();
    for (int off = 128; off >= 1; off >>= 1) {
        if (t < off) red[t] = fmaxf(red[t], red[t + off]);
        __syncthreads();
    }
    float smax = red[0];
    __syncthreads();

    float lsum = 0.f;
    for (int k = t; k < LL; k += 256) {
        float e = __expf(scores[k] - smax);
        scores[k] = e;
        lsum += e;
    }
    red[t] = lsum;
    __syncthreads();
    for (int off = 128; off >= 1; off >>= 1) {
        if (t < off) red[t] += red[t + off];
        __syncthreads();
    }
    float denom = red[0];
    __syncthreads();

    int d = t & 63, g = t >> 6;
    const float4* sc4 = (const float4*)scores;
    float acc = 0.f;
    for (int kb = g; kb < LL / 4; kb += 4) {
        float4 s4 = sc4[kb];
        int kk0 = kb * 4;
        acc = fmaf(s4.x, V[qkv_idx(b, kk0 + 0, h, d)], acc);
        acc = fmaf(s4.y, V[qkv_idx(b, kk0 + 1, h, d)], acc);
        acc = fmaf(s4.z, V[qkv_idx(b, kk0 + 2, h, d)], acc);
        acc = fmaf(s4.w, V[qkv_idx(b, kk0 + 3, h, d)], acc);
    }
    red[t] = acc;
    __syncthreads();
    if (g == 0) {
        float s = red[d] + red[64 + d] + red[128 + d] + red[192 + d];
        out[qkv_idx(b, qi, h, d)] = s / denom;
    }
}

extern "C" void kernel_launch(void* const* d_in, const int* in_sizes, int n_in,
                              void* d_out, int out_size, void* d_ws, size_t ws_size,
                              hipStream_t stream) {
    const float* Q = (const float*)d_in[0];
    const float* K = (const float*)d_in[1];
    const float* V = (const float*)d_in[2];
    const int* idx = (const int*)d_in[3];
    float* out = (float*)d_out;

    float* ws = (float*)d_ws;

    // workspace layout (floats)
    const size_t M_off = 0;                           // 65536
    const size_t tsum_off = 65536;                    // 32768
    const size_t mP_off = 98304;                      // 16*64*45 = 46080
    const size_t lP_off = 144384;                     // 46080
    const size_t top_off = 190464;                    // 720 ints (reserve 1024)
    const size_t sel_off = 191488;                    // 16*128 uints (2048)
    const size_t Op_off = 193536;                     // 16*64*45*64 = 2949120
    const size_t need = (Op_off + (size_t)BB * HH * NC * UU * DD) * 4;

    float* M = ws + M_off;
    float* tsum = ws + tsum_off;

    if (ws_size >= need) {
        float* mPart = ws + mP_off;
        float* lPart = ws + lP_off;
        int* Mtop = (int*)(ws + top_off);
        unsigned* selmap = (unsigned*)(ws + sel_off);
        float* Op = ws + Op_off;

        k_computeM_tilesum<<<NB_CM + NB_TS, 256, 0, stream>>>(Q, K, idx, V,
                                                              M, tsum);
        k_topk<<<BB * HH, 1024, 0, stream>>>(M, Mtop, selmap);
        k_attn_partial<<<BB * HH * NC, 256, 0, stream>>>(Q, K, V, Mtop,
                                                         mPart, lPart, Op);
        k_cumsum_combine<<<NB_CU + NB_CO, 256, 0, stream>>>(
            V, tsum, selmap, Mtop, mPart, lPart, Op, out);
    } else {
        // compact fallback layout
        int* Mtop = (int*)(ws + 65536);
        float* tsum2 = ws + 65536 + 1024;
        k_computeM_tilesum<<<NB_CM + NB_TS, 256, 0, stream>>>(Q, K, idx, V,
                                                              M, tsum2);
        k_topk<<<BB * HH, 1024, 0, stream>>>(M, Mtop, (unsigned*)nullptr);
        k_cumsum_fb<<<BB * HH * NTILES, 256, 0, stream>>>(V, tsum2, out);
        k_attn_mono<<<BB * HH * UU, 256, 0, stream>>>(Q, K, V, Mtop, out);
    }
}

// Round 8
// 185.149 us; speedup vs baseline: 1.2112x; 1.0122x over previous
//
#include <hip/hip_runtime.h>
#include <math.h>

#define BB 2
#define LL 4096
#define HH 8
#define DD 64
#define UU 45
#define TILE 128
#define NTILES (LL / TILE) // 32

// split-K attention config
#define NC 64              // key chunks
#define CK (LL / NC)       // 64 keys per chunk
#define KSTR 68            // padded LDS row stride (floats) for K/V/Q tiles
#define SSTR 68            // padded LDS row stride for scores (CK=64 + 4)

#define NB_CM (BB * HH * LL / 4)   // 16384 computeM blocks (4 waves each)
#define NB_TS (BB * HH * NTILES)   // 512 tilesum blocks
#define NB_CU (BB * HH * NTILES)   // 512 cumsum blocks
#define NB_CO (BB * HH * UU / 4)   // 180 combine blocks (4 u's per block)

__device__ __forceinline__ int qkv_idx(int b, int l, int h, int d) {
    return ((b * LL + l) * HH + h) * DD + d;
}

// DPP all-reduce helper: v += rotate-within-16-lane-row(v, N). VALU pipe only.
template <int CTRL>
__device__ __forceinline__ float dpp_add(float v) {
    int x = __builtin_amdgcn_update_dpp(0, __float_as_int(v), CTRL, 0xF, 0xF,
                                        true);
    return v + __int_as_float(x);
}

// ---------------- Kernel A: sparsity metric M[b,h,q]  ∥  V tile sums -----------
// computeM: one wave per query; 16 lanes per sampled K row (4 contiguous 256B
// runs per load instr -- segment-optimal). Round-7 lesson: __launch_bounds__
// (256) with no min-waves made the compiler target 8 waves/EU -> VGPR capped
// at 32 -> load batching impossible. Round-8: __launch_bounds__(256,2)
// (VGPR cap 128) + ALL 12 K-row loads issued before any use (48 data VGPRs
// in flight, one vmcnt stall per 12 loads instead of per load).
__global__ __launch_bounds__(256, 2) void k_computeM_tilesum(
        const float* __restrict__ Q, const float* __restrict__ K,
        const int* __restrict__ idx, const float* __restrict__ V,
        float* __restrict__ M, float* __restrict__ tsum) {
    if (blockIdx.x >= NB_CM) {
        // ---- tilesum branch ----
        int blk = blockIdx.x - NB_CM;  // ((b*HH+h)*NTILES + tile)
        int tile = blk % NTILES;
        int bh = blk / NTILES;
        int h = bh % HH, b = bh / HH;
        int d = threadIdx.x & 63, g = threadIdx.x >> 6; // g in 0..3
        const int CH = TILE / 4;                        // 32
        int l0 = tile * TILE + g * CH;
        float acc = 0.f;
        for (int i = 0; i < CH; ++i) acc += V[qkv_idx(b, l0 + i, h, d)];
        __shared__ float red[4][DD];
        red[g][d] = acc;
        __syncthreads();
        if (g == 0)
            tsum[blk * DD + d] =
                red[0][d] + red[1][d] + red[2][d] + red[3][d];
        return;
    }
    // ---- computeM branch ----
    int w = (blockIdx.x * blockDim.x + threadIdx.x) >> 6; // global wave id
    int lane = threadIdx.x & 63;
    int q = w % LL;
    int bh = w / LL;            // b*HH + h
    int h = bh % HH, b = bh / HH;

    const float* Kbh = K + (size_t)(b * LL * HH + h) * DD;
    const size_t rowStride = (size_t)HH * DD; // 512 floats between key rows

    int r = lane >> 4;    // which of 4 rows this lane helps load (DPP row id)
    int c16 = lane & 15;  // position within 16-lane row group

    // lane covers floats c16*4 .. c16*4+3 of both Q row and sampled K rows
    const float4 qf = *(const float4*)(Q + qkv_idx(b, q, h, c16 * 4));
    const int* idxRow = idx + q * UU;

    // preload ALL sample indices (breaks idx->Kaddr dependency chain)
    int ks[12];
#pragma unroll
    for (int g = 0; g < 12; ++g) {
        int s = g * 4 + r;
        ks[g] = idxRow[s < UU ? s : 0];  // clamped (row-end OOB guard)
    }
    // issue ALL 12 K-row loads before any consumption (48 VGPRs in flight)
    float4 kk[12];
#pragma unroll
    for (int g = 0; g < 12; ++g)
        kk[g] = ((const float4*)(Kbh + (size_t)ks[g] * rowStride))[c16];

    float mval = -INFINITY, sval = 0.f;
#pragma unroll
    for (int g = 0; g < 12; ++g) {
        float part = fmaf(kk[g].x, qf.x,
                     fmaf(kk[g].y, qf.y,
                     fmaf(kk[g].z, qf.z, kk[g].w * qf.w)));
        // all-reduce across the 16-lane row: DPP rotations (VALU pipe)
        part = dpp_add<0x128>(part); // row_ror:8
        part = dpp_add<0x124>(part); // row_ror:4
        part = dpp_add<0x122>(part); // row_ror:2
        part = dpp_add<0x121>(part); // row_ror:1
        int s = g * 4 + r;
        if (s < UU) { mval = fmaxf(mval, part); sval += part; }
    }
    // combine the 4 row groups (lanes differing in bits 4,5)
    mval = fmaxf(mval, __shfl_xor(mval, 16, 64));
    sval += __shfl_xor(sval, 16, 64);
    mval = fmaxf(mval, __shfl_xor(mval, 32, 64));
    sval += __shfl_xor(sval, 32, 64);
    if (lane == 0) M[bh * LL + q] = mval - sval * (1.0f / LL);
}

// ---------------- Kernel 2: top-45 via 4-pass radix select ---------------------
// One block of 1024 threads per (b,h) -- only 16 blocks on 256 CUs, so barrier
// latency is NOT hidden by TLP. Round-8: the 256-bin suffix scan is done by a
// single wave (4 bins/lane, shfl_down Hillis-Steele) -- ~5 barriers/pass
// instead of ~20. Emits Mtop + selmap bitmap.
__global__ __launch_bounds__(1024) void k_topk(
        const float* __restrict__ M, int* __restrict__ Mtop,
        unsigned* __restrict__ selmap) {
    int bh = blockIdx.x;
    int t = threadIdx.x;
    __shared__ unsigned keys[LL];      // 16 KB
    __shared__ unsigned hist[256];
    __shared__ unsigned scanbuf[256];
    __shared__ unsigned sPrefix, sMask, sK, sBin;
    __shared__ int outCount, eqCount;
    __shared__ int eqIdx[64];

    for (int i = t; i < LL; i += 1024) {
        unsigned u = __float_as_uint(M[bh * LL + i]);
        keys[i] = (u & 0x80000000u) ? ~u : (u | 0x80000000u);
    }
    if (selmap != nullptr && t < 128) selmap[bh * 128 + t] = 0u;
    if (t == 0) { sPrefix = 0u; sMask = 0u; sK = UU; outCount = 0; eqCount = 0; }
    __syncthreads();

    for (int pass = 0; pass < 4; ++pass) {
        int shift = 24 - pass * 8;
        if (t < 256) hist[t] = 0u;
        __syncthreads();
        unsigned prefix = sPrefix, mask = sMask;
        for (int i = t; i < LL; i += 1024) {
            unsigned k = keys[i];
            if ((k & mask) == prefix)
                atomicAdd(&hist[(k >> shift) & 0xFFu], 1u);
        }
        __syncthreads();
        // single-wave 256-bin suffix scan: lane l owns bins 4l..4l+3
        if (t < 64) {
            int l = t;
            unsigned h0 = hist[4 * l + 0], h1 = hist[4 * l + 1];
            unsigned h2 = hist[4 * l + 2], h3 = hist[4 * l + 3];
            unsigned s3 = h3, s2 = h2 + s3, s1 = h1 + s2, s0 = h0 + s1;
            unsigned tot = s0, inc = tot;
#pragma unroll
            for (int off = 1; off < 64; off <<= 1) {
                unsigned x = __shfl_down(inc, off, 64);
                if (l + off < 64) inc += x;
            }
            unsigned above = inc - tot; // sum over lanes > l
            scanbuf[4 * l + 0] = s0 + above;
            scanbuf[4 * l + 1] = s1 + above;
            scanbuf[4 * l + 2] = s2 + above;
            scanbuf[4 * l + 3] = s3 + above;
        }
        __syncthreads();
        if (t < 256) {
            unsigned k = sK;
            unsigned geq = scanbuf[t];
            unsigned gt = (t < 255) ? scanbuf[t + 1] : 0u;
            if (gt < k && geq >= k) sBin = (unsigned)t;
        }
        __syncthreads();
        if (t == 0) {
            unsigned b = sBin;
            unsigned gt = (b < 255u) ? scanbuf[b + 1] : 0u;
            sK -= gt;
            sPrefix |= (b << shift);
            sMask |= (0xFFu << shift);
        }
        __syncthreads();
    }
    unsigned T = sPrefix;
    int kEq = (int)sK;

    for (int i = t; i < LL; i += 1024) {
        unsigned k = keys[i];
        if (k > T) {
            int slot = atomicAdd(&outCount, 1);
            Mtop[bh * UU + slot] = i;
        } else if (k == T) {
            int e = atomicAdd(&eqCount, 1);
            if (e < 64) eqIdx[e] = i;
        }
    }
    __syncthreads();

    if (t == 0) {
        int base = outCount; // == UU - kEq
        int ec = eqCount;
        if (ec <= 64) {
            for (int s = 0; s < UU; ++s) { // s < kEq, bounded loop for compiler
                if (s >= kEq) break;
                int bi = -1, bv = LL + 2;
                for (int j = 0; j < ec; ++j) {
                    int v = eqIdx[j];
                    if (v < bv) { bv = v; bi = j; }
                }
                Mtop[bh * UU + base + s] = bv;
                eqIdx[bi] = LL + 2;
            }
        } else {
            // paranoid fallback (massive duplicate values): serial lowest-index
            int got = 0;
            for (int i = 0; i < LL && got < kEq; ++i)
                if (keys[i] == T) { Mtop[bh * UU + base + got] = i; ++got; }
        }
    }
    __syncthreads();
    if (selmap != nullptr && t < UU) {
        int qi = Mtop[bh * UU + t];
        atomicOr(&selmap[bh * 128 + (qi >> 5)], 1u << (qi & 31));
    }
}

// ---------------- Kernel 5a: split-K flash attention partials ------------------
__global__ __launch_bounds__(256) void k_attn_partial(
        const float* __restrict__ Q, const float* __restrict__ K,
        const float* __restrict__ V, const int* __restrict__ Mtop,
        float* __restrict__ mPart, float* __restrict__ lPart,
        float* __restrict__ Op) {
    int blk = blockIdx.x;      // bh * NC + c
    int c = blk % NC;
    int bh = blk / NC;
    int h = bh % HH, b = bh / HH;
    int k0 = c * CK;
    int t = threadIdx.x;

    __shared__ float Qs[48 * KSTR];   // 13056 B (rows 45..47 zeroed)
    __shared__ float Ks[CK * KSTR];   // 17408 B (reused for V in PV phase)
    __shared__ float Ss[UU * SSTR];   // 12240 B

    const size_t rowStride = (size_t)HH * DD; // 512 floats
    const float* Qbh = Q + (size_t)(b * LL * HH + h) * DD;
    const float* Kbh = K + (size_t)(b * LL * HH + h) * DD;
    const float* Vbh = V + (size_t)(b * LL * HH + h) * DD;

    for (int p = t; p < 48 * DD; p += 256) {
        int u = p >> 6, d = p & 63;
        float v = 0.f;
        if (u < UU) {
            int qi = Mtop[bh * UU + u];
            v = Qbh[(size_t)qi * rowStride + d] * 0.125f;
        }
        Qs[u * KSTR + d] = v;
    }
    for (int p = t; p < CK * 16; p += 256) {
        int row = p >> 4, i = p & 15;
        *(float4*)&Ks[row * KSTR + i * 4] =
            *(const float4*)&Kbh[(size_t)(k0 + row) * rowStride + i * 4];
    }
    __syncthreads();

    // --- scores GEMM: thread tile 3u x 4k ---
    int kq = t & 15, uq = t >> 4;
    int u0 = uq * 3;
    float acc[3][4];
#pragma unroll
    for (int i = 0; i < 3; ++i)
#pragma unroll
        for (int j = 0; j < 4; ++j) acc[i][j] = 0.f;

#pragma unroll 4
    for (int dd = 0; dd < 16; ++dd) {
        float4 qf[3];
#pragma unroll
        for (int i = 0; i < 3; ++i)
            qf[i] = *(const float4*)&Qs[(u0 + i) * KSTR + dd * 4];
        float4 kf[4];
#pragma unroll
        for (int j = 0; j < 4; ++j)
            kf[j] = *(const float4*)&Ks[(kq + 16 * j) * KSTR + dd * 4];
#pragma unroll
        for (int i = 0; i < 3; ++i)
#pragma unroll
            for (int j = 0; j < 4; ++j) {
                acc[i][j] = fmaf(qf[i].x, kf[j].x, acc[i][j]);
                acc[i][j] = fmaf(qf[i].y, kf[j].y, acc[i][j]);
                acc[i][j] = fmaf(qf[i].z, kf[j].z, acc[i][j]);
                acc[i][j] = fmaf(qf[i].w, kf[j].w, acc[i][j]);
            }
    }
#pragma unroll
    for (int i = 0; i < 3; ++i) {
        int u = u0 + i;
        if (u < UU)
#pragma unroll
            for (int j = 0; j < 4; ++j) Ss[u * SSTR + kq + 16 * j] = acc[i][j];
    }
    __syncthreads();

    // stage V chunk into the K buffer (no one reads Ks until next barrier)
    for (int p = t; p < CK * 16; p += 256) {
        int row = p >> 4, i = p & 15;
        *(float4*)&Ks[row * KSTR + i * 4] =
            *(const float4*)&Vbh[(size_t)(k0 + row) * rowStride + i * 4];
    }

    // --- chunk-local softmax: 4 threads per u ---
    if (t < UU * 4) {
        int u = t >> 2, qq = t & 3;
        float mloc = -INFINITY;
        for (int j = 0; j < CK / 4; ++j)
            mloc = fmaxf(mloc, Ss[u * SSTR + qq + 4 * j]);
        mloc = fmaxf(mloc, __shfl_xor(mloc, 1, 64));
        mloc = fmaxf(mloc, __shfl_xor(mloc, 2, 64));
        float lloc = 0.f;
        for (int j = 0; j < CK / 4; ++j) {
            int kk = qq + 4 * j;
            float e = __expf(Ss[u * SSTR + kk] - mloc);
            Ss[u * SSTR + kk] = e;
            lloc += e;
        }
        lloc += __shfl_xor(lloc, 1, 64);
        lloc += __shfl_xor(lloc, 2, 64);
        if (qq == 0) {
            mPart[(bh * NC + c) * UU + u] = mloc;
            lPart[(bh * NC + c) * UU + u] = lloc;
        }
    }
    __syncthreads();

    // --- PV GEMM: thread tile 3u x 4d ---
    int dq = t & 15;
    int d0 = dq * 4;
    if (u0 < UU) { // uq==15 idle
        float4 o[3];
#pragma unroll
        for (int i = 0; i < 3; ++i) o[i] = make_float4(0.f, 0.f, 0.f, 0.f);
#pragma unroll 4
        for (int kc = 0; kc < CK / 4; ++kc) {
            float4 vk[4];
#pragma unroll
            for (int jj = 0; jj < 4; ++jj)
                vk[jj] = *(const float4*)&Ks[(4 * kc + jj) * KSTR + d0];
#pragma unroll
            for (int i = 0; i < 3; ++i) {
                float4 pf = *(const float4*)&Ss[(u0 + i) * SSTR + 4 * kc];
                o[i].x = fmaf(pf.x, vk[0].x, o[i].x);
                o[i].y = fmaf(pf.x, vk[0].y, o[i].y);
                o[i].z = fmaf(pf.x, vk[0].z, o[i].z);
                o[i].w = fmaf(pf.x, vk[0].w, o[i].w);
                o[i].x = fmaf(pf.y, vk[1].x, o[i].x);
                o[i].y = fmaf(pf.y, vk[1].y, o[i].y);
                o[i].z = fmaf(pf.y, vk[1].z, o[i].z);
                o[i].w = fmaf(pf.y, vk[1].w, o[i].w);
                o[i].x = fmaf(pf.z, vk[2].x, o[i].x);
                o[i].y = fmaf(pf.z, vk[2].y, o[i].y);
                o[i].z = fmaf(pf.z, vk[2].z, o[i].z);
                o[i].w = fmaf(pf.z, vk[2].w, o[i].w);
                o[i].x = fmaf(pf.w, vk[3].x, o[i].x);
                o[i].y = fmaf(pf.w, vk[3].y, o[i].y);
                o[i].z = fmaf(pf.w, vk[3].z, o[i].z);
                o[i].w = fmaf(pf.w, vk[3].w, o[i].w);
            }
        }
#pragma unroll
        for (int i = 0; i < 3; ++i) {
            int u = u0 + i;
            *(float4*)&Op[((size_t)(bh * NC + c) * UU + u) * DD + d0] = o[i];
        }
    }
}

// ---------------- Kernel B: cumsum(V)  ∥  flash combine (disjoint rows) --------
__global__ __launch_bounds__(256) void k_cumsum_combine(
        const float* __restrict__ V, const float* __restrict__ tsum,
        const unsigned* __restrict__ selmap, const int* __restrict__ Mtop,
        const float* __restrict__ mPart, const float* __restrict__ lPart,
        const float* __restrict__ Op, float* __restrict__ out) {
    int t = threadIdx.x;
    if (blockIdx.x >= NB_CU) {
        // ---- combine branch: 4 u-slots per block, 64 threads each ----
        int u4 = (blockIdx.x - NB_CU) * 4 + (t >> 6); // 0..719
        int u = u4 % UU;
        int bh = u4 / UU;
        int h = bh % HH, b = bh / HH;
        int d = t & 63;
        float gm = -INFINITY;
        for (int c = 0; c < NC; ++c)
            gm = fmaxf(gm, mPart[(bh * NC + c) * UU + u]);
        float denom = 0.f, acc = 0.f;
        for (int c = 0; c < NC; ++c) {
            int pi = (bh * NC + c) * UU + u;
            float w = __expf(mPart[pi] - gm);
            denom = fmaf(lPart[pi], w, denom);
            acc = fmaf(w, Op[(size_t)pi * DD + d], acc);
        }
        int qi = Mtop[bh * UU + u];
        out[qkv_idx(b, qi, h, d)] = acc / denom;
        return;
    }
    // ---- cumsum branch ----
    int blk = blockIdx.x;
    int tile = blk % NTILES;
    int bh = blk / NTILES;
    int h = bh % HH, b = bh / HH;
    int d = t & 63, g = t >> 6;
    const int CH = TILE / 4;
    int l0 = tile * TILE + g * CH;

    __shared__ float red[4][DD];
    __shared__ float pre2[4][DD];
    float acc = 0.f;
    for (int i = 0; i < CH; ++i) acc += V[qkv_idx(b, l0 + i, h, d)];
    red[g][d] = acc;
    float p = 0.f;
    for (int tt = g; tt < tile; tt += 4)
        p += tsum[(bh * NTILES + tt) * DD + d];
    pre2[g][d] = p;
    __syncthreads();

    float off = pre2[0][d] + pre2[1][d] + pre2[2][d] + pre2[3][d];
    for (int gg = 0; gg < g; ++gg) off += red[gg][d];

    // rows l0..l0+31 share one bitmap word: l>>5 == tile*4+g
    unsigned selw = selmap[bh * 128 + (l0 >> 5)];

    float run = off;
    for (int i = 0; i < CH; ++i) {
        run += V[qkv_idx(b, l0 + i, h, d)];
        if (!((selw >> i) & 1u))
            out[qkv_idx(b, l0 + i, h, d)] = run;
    }
}

// ---------------- Fallback-path kernels ----------------------------------------
__global__ __launch_bounds__(256) void k_cumsum_fb(
        const float* __restrict__ V, const float* __restrict__ tsum,
        float* __restrict__ out) {
    int blk = blockIdx.x;
    int tile = blk % NTILES;
    int bh = blk / NTILES;
    int h = bh % HH, b = bh / HH;
    int t = threadIdx.x;
    int d = t & 63, g = t >> 6;
    const int CH = TILE / 4;
    int l0 = tile * TILE + g * CH;

    __shared__ float red[4][DD];
    __shared__ float pre2[4][DD];
    float acc = 0.f;
    for (int i = 0; i < CH; ++i) acc += V[qkv_idx(b, l0 + i, h, d)];
    red[g][d] = acc;
    float p = 0.f;
    for (int tt = g; tt < tile; tt += 4)
        p += tsum[(bh * NTILES + tt) * DD + d];
    pre2[g][d] = p;
    __syncthreads();

    float off = pre2[0][d] + pre2[1][d] + pre2[2][d] + pre2[3][d];
    for (int gg = 0; gg < g; ++gg) off += red[gg][d];

    float run = off;
    for (int i = 0; i < CH; ++i) {
        run += V[qkv_idx(b, l0 + i, h, d)];
        out[qkv_idx(b, l0 + i, h, d)] = run;
    }
}

__global__ __launch_bounds__(256) void k_attn_mono(
        const float* __restrict__ Q, const float* __restrict__ K,
        const float* __restrict__ V, const int* __restrict__ Mtop,
        float* __restrict__ out) {
    int blk = blockIdx.x; // bh*UU + u
    int u = blk % UU;
    int bh = blk / UU;
    int h = bh % HH, b = bh / HH;
    int qi = Mtop[bh * UU + u];
    int t = threadIdx.x;

    __shared__ float scores[LL];
    __shared__ float red[256];

    const float4* qp = (const float4*)(Q + qkv_idx(b, qi, h, 0));
    float4 qreg[16];
#pragma unroll
    for (int i = 0; i < 16; ++i) {
        float4 v = qp[i];
        v.x *= 0.125f; v.y *= 0.125f; v.z *= 0.125f; v.w *= 0.125f;
        qreg[i] = v;
    }

    float lmax = -INFINITY;
    for (int k = t; k < LL; k += 256) {
        const float4* kr = (const float4*)(K + qkv_idx(b, k, h, 0));
        float dot = 0.f;
#pragma unroll
        for (int i = 0; i < 16; ++i) {
            float4 kk = kr[i];
            dot = fmaf(qreg[i].x, kk.x, dot);
            dot = fmaf(qreg[i].y, kk.y, dot);
            dot = fmaf(qreg[i].z, kk.z, dot);
            dot = fmaf(qreg[i].w, kk.w, dot);
        }
        scores[k] = dot;
        lmax = fmaxf(lmax, dot);
    }
    red[t] = lmax;
    __syncthreads();
    for (int off = 128; off >= 1; off >>= 1) {
        if (t < off) red[t] = fmaxf(red[t], red[t + off]);
        __syncthreads();
    }
    float smax = red[0];
    __syncthreads();

    float lsum = 0.f;
    for (int k = t; k < LL; k += 256) {
        float e = __expf(scores[k] - smax);
        scores[k] = e;
        lsum += e;
    }
    red[t] = lsum;
    __syncthreads();
    for (int off = 128; off >= 1; off >>= 1) {
        if (t < off) red[t] += red[t + off];
        __syncthreads();
    }
    float denom = red[0];
    __syncthreads();

    int d = t & 63, g = t >> 6;
    const float4* sc4 = (const float4*)scores;
    float acc = 0.f;
    for (int kb = g; kb < LL / 4; kb += 4) {
        float4 s4 = sc4[kb];
        int kk0 = kb * 4;
        acc = fmaf(s4.x, V[qkv_idx(b, kk0 + 0, h, d)], acc);
        acc = fmaf(s4.y, V[qkv_idx(b, kk0 + 1, h, d)], acc);
        acc = fmaf(s4.z, V[qkv_idx(b, kk0 + 2, h, d)], acc);
        acc = fmaf(s4.w, V[qkv_idx(b, kk0 + 3, h, d)], acc);
    }
    red[t] = acc;
    __syncthreads();
    if (g == 0) {
        float s = red[d] + red[64 + d] + red[128 + d] + red[192 + d];
        out[qkv_idx(b, qi, h, d)] = s / denom;
    }
}

extern "C" void kernel_launch(void* const* d_in, const int* in_sizes, int n_in,
                              void* d_out, int out_size, void* d_ws, size_t ws_size,
                              hipStream_t stream) {
    const float* Q = (const float*)d_in[0];
    const float* K = (const float*)d_in[1];
    const float* V = (const float*)d_in[2];
    const int* idx = (const int*)d_in[3];
    float* out = (float*)d_out;

    float* ws = (float*)d_ws;

    // workspace layout (floats)
    const size_t M_off = 0;                           // 65536
    const size_t tsum_off = 65536;                    // 32768
    const size_t mP_off = 98304;                      // 16*64*45 = 46080
    const size_t lP_off = 144384;                     // 46080
    const size_t top_off = 190464;                    // 720 ints (reserve 1024)
    const size_t sel_off = 191488;                    // 16*128 uints (2048)
    const size_t Op_off = 193536;                     // 16*64*45*64 = 2949120
    const size_t need = (Op_off + (size_t)BB * HH * NC * UU * DD) * 4;

    float* M = ws + M_off;
    float* tsum = ws + tsum_off;

    if (ws_size >= need) {
        float* mPart = ws + mP_off;
        float* lPart = ws + lP_off;
        int* Mtop = (int*)(ws + top_off);
        unsigned* selmap = (unsigned*)(ws + sel_off);
        float* Op = ws + Op_off;

        k_computeM_tilesum<<<NB_CM + NB_TS, 256, 0, stream>>>(Q, K, idx, V,
                                                              M, tsum);
        k_topk<<<BB * HH, 1024, 0, stream>>>(M, Mtop, selmap);
        k_attn_partial<<<BB * HH * NC, 256, 0, stream>>>(Q, K, V, Mtop,
                                                         mPart, lPart, Op);
        k_cumsum_combine<<<NB_CU + NB_CO, 256, 0, stream>>>(
            V, tsum, selmap, Mtop, mPart, lPart, Op, out);
    } else {
        // compact fallback layout
        int* Mtop = (int*)(ws + 65536);
        float* tsum2 = ws + 65536 + 1024;
        k_computeM_tilesum<<<NB_CM + NB_TS, 256, 0, stream>>>(Q, K, idx, V,
                                                              M, tsum2);
        k_topk<<<BB * HH, 1024, 0, stream>>>(M, Mtop, (unsigned*)nullptr);
        k_cumsum_fb<<<BB * HH * NTILES, 256, 0, stream>>>(V, tsum2, out);
        k_attn_mono<<<BB * HH * UU, 256, 0, stream>>>(Q, K, V, Mtop, out);
    }
}

// Round 9
// 184.255 us; speedup vs baseline: 1.2171x; 1.0049x over previous
//
#include <hip/hip_runtime.h>
#include <math.h>

#define BB 2
#define LL 4096
#define HH 8
#define DD 64
#define UU 45
#define TILE 128
#define NTILES (LL / TILE) // 32

// split-K attention config
#define NC 64              // key chunks
#define CK (LL / NC)       // 64 keys per chunk
#define KSTR 68            // padded LDS row stride (floats) for K/V/Q tiles
#define SSTR 68            // padded LDS row stride for scores (CK=64 + 4)

#define NB_CM (BB * HH * LL / 4)   // 16384 computeM blocks (4 waves each)
#define NB_TS (BB * HH * NTILES)   // 512 tilesum blocks
#define NB_CU (BB * HH * NTILES)   // 512 cumsum blocks
#define NB_CO (BB * HH * UU / 4)   // 180 combine blocks (4 u's per block)

__device__ __forceinline__ int qkv_idx(int b, int l, int h, int d) {
    return ((b * LL + l) * HH + h) * DD + d;
}

// DPP all-reduce helper: v += rotate-within-16-lane-row(v, N). VALU pipe only.
template <int CTRL>
__device__ __forceinline__ float dpp_add(float v) {
    int x = __builtin_amdgcn_update_dpp(0, __float_as_int(v), CTRL, 0xF, 0xF,
                                        true);
    return v + __int_as_float(x);
}

// ---------------- Kernel A: sparsity metric M[b,h,q]  ∥  V tile sums -----------
// computeM: one wave per query; 16 lanes per sampled K row (4 contiguous 256B
// runs per load instr -- segment-optimal). Round-8 lesson: VGPR stayed 32 with
// __launch_bounds__(256,2) -- the machine scheduler SANK each K-load to just
// before its use (minimizing live ranges), re-serializing the batch. Round-9:
// __builtin_amdgcn_sched_barrier(0) after the load batch pins all 12
// global_load_dwordx4 before the first FMA -> counted vmcnt(11..0) pipeline,
// one latency stall per 12 loads instead of per load.
__global__ __launch_bounds__(256, 2) void k_computeM_tilesum(
        const float* __restrict__ Q, const float* __restrict__ K,
        const int* __restrict__ idx, const float* __restrict__ V,
        float* __restrict__ M, float* __restrict__ tsum) {
    if (blockIdx.x >= NB_CM) {
        // ---- tilesum branch ----
        int blk = blockIdx.x - NB_CM;  // ((b*HH+h)*NTILES + tile)
        int tile = blk % NTILES;
        int bh = blk / NTILES;
        int h = bh % HH, b = bh / HH;
        int d = threadIdx.x & 63, g = threadIdx.x >> 6; // g in 0..3
        const int CH = TILE / 4;                        // 32
        int l0 = tile * TILE + g * CH;
        float acc = 0.f;
        for (int i = 0; i < CH; ++i) acc += V[qkv_idx(b, l0 + i, h, d)];
        __shared__ float red[4][DD];
        red[g][d] = acc;
        __syncthreads();
        if (g == 0)
            tsum[blk * DD + d] =
                red[0][d] + red[1][d] + red[2][d] + red[3][d];
        return;
    }
    // ---- computeM branch ----
    int w = (blockIdx.x * blockDim.x + threadIdx.x) >> 6; // global wave id
    int lane = threadIdx.x & 63;
    int q = w % LL;
    int bh = w / LL;            // b*HH + h
    int h = bh % HH, b = bh / HH;

    const float* Kbh = K + (size_t)(b * LL * HH + h) * DD;
    const size_t rowStride = (size_t)HH * DD; // 512 floats between key rows

    int r = lane >> 4;    // which of 4 rows this lane helps load (DPP row id)
    int c16 = lane & 15;  // position within 16-lane row group

    // lane covers floats c16*4 .. c16*4+3 of both Q row and sampled K rows
    const float4 qf = *(const float4*)(Q + qkv_idx(b, q, h, c16 * 4));
    const int* idxRow = idx + q * UU;

    // preload ALL sample indices (breaks idx->Kaddr dependency chain)
    int ks[12];
#pragma unroll
    for (int g = 0; g < 12; ++g) {
        int s = g * 4 + r;
        ks[g] = idxRow[s < UU ? s : 0];  // clamped (row-end OOB guard)
    }
    // keep the idx loads batched ahead of the K-address math
    __builtin_amdgcn_sched_barrier(0);

    // issue ALL 12 K-row loads before any consumption (48 VGPRs in flight)
    float4 kk[12];
#pragma unroll
    for (int g = 0; g < 12; ++g)
        kk[g] = ((const float4*)(Kbh + (size_t)ks[g] * rowStride))[c16];
    // pin: no FMA may hoist above, no load may sink below -> counted vmcnt
    __builtin_amdgcn_sched_barrier(0);

    float mval = -INFINITY, sval = 0.f;
#pragma unroll
    for (int g = 0; g < 12; ++g) {
        float part = fmaf(kk[g].x, qf.x,
                     fmaf(kk[g].y, qf.y,
                     fmaf(kk[g].z, qf.z, kk[g].w * qf.w)));
        // all-reduce across the 16-lane row: DPP rotations (VALU pipe)
        part = dpp_add<0x128>(part); // row_ror:8
        part = dpp_add<0x124>(part); // row_ror:4
        part = dpp_add<0x122>(part); // row_ror:2
        part = dpp_add<0x121>(part); // row_ror:1
        int s = g * 4 + r;
        if (s < UU) { mval = fmaxf(mval, part); sval += part; }
    }
    // combine the 4 row groups (lanes differing in bits 4,5)
    mval = fmaxf(mval, __shfl_xor(mval, 16, 64));
    sval += __shfl_xor(sval, 16, 64);
    mval = fmaxf(mval, __shfl_xor(mval, 32, 64));
    sval += __shfl_xor(sval, 32, 64);
    if (lane == 0) M[bh * LL + q] = mval - sval * (1.0f / LL);
}

// ---------------- Kernel 2: top-45 via 4-pass radix select ---------------------
// One block of 1024 threads per (b,h) -- only 16 blocks on 256 CUs, so barrier
// latency is NOT hidden by TLP. Single-wave 256-bin suffix scan (4 bins/lane,
// shfl_down Hillis-Steele). Emits Mtop + selmap bitmap.
__global__ __launch_bounds__(1024) void k_topk(
        const float* __restrict__ M, int* __restrict__ Mtop,
        unsigned* __restrict__ selmap) {
    int bh = blockIdx.x;
    int t = threadIdx.x;
    __shared__ unsigned keys[LL];      // 16 KB
    __shared__ unsigned hist[256];
    __shared__ unsigned scanbuf[256];
    __shared__ unsigned sPrefix, sMask, sK, sBin;
    __shared__ int outCount, eqCount;
    __shared__ int eqIdx[64];

    for (int i = t; i < LL; i += 1024) {
        unsigned u = __float_as_uint(M[bh * LL + i]);
        keys[i] = (u & 0x80000000u) ? ~u : (u | 0x80000000u);
    }
    if (selmap != nullptr && t < 128) selmap[bh * 128 + t] = 0u;
    if (t == 0) { sPrefix = 0u; sMask = 0u; sK = UU; outCount = 0; eqCount = 0; }
    __syncthreads();

    for (int pass = 0; pass < 4; ++pass) {
        int shift = 24 - pass * 8;
        if (t < 256) hist[t] = 0u;
        __syncthreads();
        unsigned prefix = sPrefix, mask = sMask;
        for (int i = t; i < LL; i += 1024) {
            unsigned k = keys[i];
            if ((k & mask) == prefix)
                atomicAdd(&hist[(k >> shift) & 0xFFu], 1u);
        }
        __syncthreads();
        // single-wave 256-bin suffix scan: lane l owns bins 4l..4l+3
        if (t < 64) {
            int l = t;
            unsigned h0 = hist[4 * l + 0], h1 = hist[4 * l + 1];
            unsigned h2 = hist[4 * l + 2], h3 = hist[4 * l + 3];
            unsigned s3 = h3, s2 = h2 + s3, s1 = h1 + s2, s0 = h0 + s1;
            unsigned tot = s0, inc = tot;
#pragma unroll
            for (int off = 1; off < 64; off <<= 1) {
                unsigned x = __shfl_down(inc, off, 64);
                if (l + off < 64) inc += x;
            }
            unsigned above = inc - tot; // sum over lanes > l
            scanbuf[4 * l + 0] = s0 + above;
            scanbuf[4 * l + 1] = s1 + above;
            scanbuf[4 * l + 2] = s2 + above;
            scanbuf[4 * l + 3] = s3 + above;
        }
        __syncthreads();
        if (t < 256) {
            unsigned k = sK;
            unsigned geq = scanbuf[t];
            unsigned gt = (t < 255) ? scanbuf[t + 1] : 0u;
            if (gt < k && geq >= k) sBin = (unsigned)t;
        }
        __syncthreads();
        if (t == 0) {
            unsigned b = sBin;
            unsigned gt = (b < 255u) ? scanbuf[b + 1] : 0u;
            sK -= gt;
            sPrefix |= (b << shift);
            sMask |= (0xFFu << shift);
        }
        __syncthreads();
    }
    unsigned T = sPrefix;
    int kEq = (int)sK;

    for (int i = t; i < LL; i += 1024) {
        unsigned k = keys[i];
        if (k > T) {
            int slot = atomicAdd(&outCount, 1);
            Mtop[bh * UU + slot] = i;
        } else if (k == T) {
            int e = atomicAdd(&eqCount, 1);
            if (e < 64) eqIdx[e] = i;
        }
    }
    __syncthreads();

    if (t == 0) {
        int base = outCount; // == UU - kEq
        int ec = eqCount;
        if (ec <= 64) {
            for (int s = 0; s < UU; ++s) { // s < kEq, bounded loop for compiler
                if (s >= kEq) break;
                int bi = -1, bv = LL + 2;
                for (int j = 0; j < ec; ++j) {
                    int v = eqIdx[j];
                    if (v < bv) { bv = v; bi = j; }
                }
                Mtop[bh * UU + base + s] = bv;
                eqIdx[bi] = LL + 2;
            }
        } else {
            // paranoid fallback (massive duplicate values): serial lowest-index
            int got = 0;
            for (int i = 0; i < LL && got < kEq; ++i)
                if (keys[i] == T) { Mtop[bh * UU + base + got] = i; ++got; }
        }
    }
    __syncthreads();
    if (selmap != nullptr && t < UU) {
        int qi = Mtop[bh * UU + t];
        atomicOr(&selmap[bh * 128 + (qi >> 5)], 1u << (qi & 31));
    }
}

// ---------------- Kernel 5a: split-K flash attention partials ------------------
__global__ __launch_bounds__(256) void k_attn_partial(
        const float* __restrict__ Q, const float* __restrict__ K,
        const float* __restrict__ V, const int* __restrict__ Mtop,
        float* __restrict__ mPart, float* __restrict__ lPart,
        float* __restrict__ Op) {
    int blk = blockIdx.x;      // bh * NC + c
    int c = blk % NC;
    int bh = blk / NC;
    int h = bh % HH, b = bh / HH;
    int k0 = c * CK;
    int t = threadIdx.x;

    __shared__ float Qs[48 * KSTR];   // 13056 B (rows 45..47 zeroed)
    __shared__ float Ks[CK * KSTR];   // 17408 B (reused for V in PV phase)
    __shared__ float Ss[UU * SSTR];   // 12240 B

    const size_t rowStride = (size_t)HH * DD; // 512 floats
    const float* Qbh = Q + (size_t)(b * LL * HH + h) * DD;
    const float* Kbh = K + (size_t)(b * LL * HH + h) * DD;
    const float* Vbh = V + (size_t)(b * LL * HH + h) * DD;

    for (int p = t; p < 48 * DD; p += 256) {
        int u = p >> 6, d = p & 63;
        float v = 0.f;
        if (u < UU) {
            int qi = Mtop[bh * UU + u];
            v = Qbh[(size_t)qi * rowStride + d] * 0.125f;
        }
        Qs[u * KSTR + d] = v;
    }
    for (int p = t; p < CK * 16; p += 256) {
        int row = p >> 4, i = p & 15;
        *(float4*)&Ks[row * KSTR + i * 4] =
            *(const float4*)&Kbh[(size_t)(k0 + row) * rowStride + i * 4];
    }
    __syncthreads();

    // --- scores GEMM: thread tile 3u x 4k ---
    int kq = t & 15, uq = t >> 4;
    int u0 = uq * 3;
    float acc[3][4];
#pragma unroll
    for (int i = 0; i < 3; ++i)
#pragma unroll
        for (int j = 0; j < 4; ++j) acc[i][j] = 0.f;

#pragma unroll 4
    for (int dd = 0; dd < 16; ++dd) {
        float4 qf[3];
#pragma unroll
        for (int i = 0; i < 3; ++i)
            qf[i] = *(const float4*)&Qs[(u0 + i) * KSTR + dd * 4];
        float4 kf[4];
#pragma unroll
        for (int j = 0; j < 4; ++j)
            kf[j] = *(const float4*)&Ks[(kq + 16 * j) * KSTR + dd * 4];
#pragma unroll
        for (int i = 0; i < 3; ++i)
#pragma unroll
            for (int j = 0; j < 4; ++j) {
                acc[i][j] = fmaf(qf[i].x, kf[j].x, acc[i][j]);
                acc[i][j] = fmaf(qf[i].y, kf[j].y, acc[i][j]);
                acc[i][j] = fmaf(qf[i].z, kf[j].z, acc[i][j]);
                acc[i][j] = fmaf(qf[i].w, kf[j].w, acc[i][j]);
            }
    }
#pragma unroll
    for (int i = 0; i < 3; ++i) {
        int u = u0 + i;
        if (u < UU)
#pragma unroll
            for (int j = 0; j < 4; ++j) Ss[u * SSTR + kq + 16 * j] = acc[i][j];
    }
    __syncthreads();

    // stage V chunk into the K buffer (no one reads Ks until next barrier)
    for (int p = t; p < CK * 16; p += 256) {
        int row = p >> 4, i = p & 15;
        *(float4*)&Ks[row * KSTR + i * 4] =
            *(const float4*)&Vbh[(size_t)(k0 + row) * rowStride + i * 4];
    }

    // --- chunk-local softmax: 4 threads per u ---
    if (t < UU * 4) {
        int u = t >> 2, qq = t & 3;
        float mloc = -INFINITY;
        for (int j = 0; j < CK / 4; ++j)
            mloc = fmaxf(mloc, Ss[u * SSTR + qq + 4 * j]);
        mloc = fmaxf(mloc, __shfl_xor(mloc, 1, 64));
        mloc = fmaxf(mloc, __shfl_xor(mloc, 2, 64));
        float lloc = 0.f;
        for (int j = 0; j < CK / 4; ++j) {
            int kk = qq + 4 * j;
            float e = __expf(Ss[u * SSTR + kk] - mloc);
            Ss[u * SSTR + kk] = e;
            lloc += e;
        }
        lloc += __shfl_xor(lloc, 1, 64);
        lloc += __shfl_xor(lloc, 2, 64);
        if (qq == 0) {
            mPart[(bh * NC + c) * UU + u] = mloc;
            lPart[(bh * NC + c) * UU + u] = lloc;
        }
    }
    __syncthreads();

    // --- PV GEMM: thread tile 3u x 4d ---
    int dq = t & 15;
    int d0 = dq * 4;
    if (u0 < UU) { // uq==15 idle
        float4 o[3];
#pragma unroll
        for (int i = 0; i < 3; ++i) o[i] = make_float4(0.f, 0.f, 0.f, 0.f);
#pragma unroll 4
        for (int kc = 0; kc < CK / 4; ++kc) {
            float4 vk[4];
#pragma unroll
            for (int jj = 0; jj < 4; ++jj)
                vk[jj] = *(const float4*)&Ks[(4 * kc + jj) * KSTR + d0];
#pragma unroll
            for (int i = 0; i < 3; ++i) {
                float4 pf = *(const float4*)&Ss[(u0 + i) * SSTR + 4 * kc];
                o[i].x = fmaf(pf.x, vk[0].x, o[i].x);
                o[i].y = fmaf(pf.x, vk[0].y, o[i].y);
                o[i].z = fmaf(pf.x, vk[0].z, o[i].z);
                o[i].w = fmaf(pf.x, vk[0].w, o[i].w);
                o[i].x = fmaf(pf.y, vk[1].x, o[i].x);
                o[i].y = fmaf(pf.y, vk[1].y, o[i].y);
                o[i].z = fmaf(pf.y, vk[1].z, o[i].z);
                o[i].w = fmaf(pf.y, vk[1].w, o[i].w);
                o[i].x = fmaf(pf.z, vk[2].x, o[i].x);
                o[i].y = fmaf(pf.z, vk[2].y, o[i].y);
                o[i].z = fmaf(pf.z, vk[2].z, o[i].z);
                o[i].w = fmaf(pf.z, vk[2].w, o[i].w);
                o[i].x = fmaf(pf.w, vk[3].x, o[i].x);
                o[i].y = fmaf(pf.w, vk[3].y, o[i].y);
                o[i].z = fmaf(pf.w, vk[3].z, o[i].z);
                o[i].w = fmaf(pf.w, vk[3].w, o[i].w);
            }
        }
#pragma unroll
        for (int i = 0; i < 3; ++i) {
            int u = u0 + i;
            *(float4*)&Op[((size_t)(bh * NC + c) * UU + u) * DD + d0] = o[i];
        }
    }
}

// ---------------- Kernel B: cumsum(V)  ∥  flash combine (disjoint rows) --------
__global__ __launch_bounds__(256) void k_cumsum_combine(
        const float* __restrict__ V, const float* __restrict__ tsum,
        const unsigned* __restrict__ selmap, const int* __restrict__ Mtop,
        const float* __restrict__ mPart, const float* __restrict__ lPart,
        const float* __restrict__ Op, float* __restrict__ out) {
    int t = threadIdx.x;
    if (blockIdx.x >= NB_CU) {
        // ---- combine branch: 4 u-slots per block, 64 threads each ----
        int u4 = (blockIdx.x - NB_CU) * 4 + (t >> 6); // 0..719
        int u = u4 % UU;
        int bh = u4 / UU;
        int h = bh % HH, b = bh / HH;
        int d = t & 63;
        float gm = -INFINITY;
        for (int c = 0; c < NC; ++c)
            gm = fmaxf(gm, mPart[(bh * NC + c) * UU + u]);
        float denom = 0.f, acc = 0.f;
        for (int c = 0; c < NC; ++c) {
            int pi = (bh * NC + c) * UU + u;
            float w = __expf(mPart[pi] - gm);
            denom = fmaf(lPart[pi], w, denom);
            acc = fmaf(w, Op[(size_t)pi * DD + d], acc);
        }
        int qi = Mtop[bh * UU + u];
        out[qkv_idx(b, qi, h, d)] = acc / denom;
        return;
    }
    // ---- cumsum branch ----
    int blk = blockIdx.x;
    int tile = blk % NTILES;
    int bh = blk / NTILES;
    int h = bh % HH, b = bh / HH;
    int d = t & 63, g = t >> 6;
    const int CH = TILE / 4;
    int l0 = tile * TILE + g * CH;

    __shared__ float red[4][DD];
    __shared__ float pre2[4][DD];
    float acc = 0.f;
    for (int i = 0; i < CH; ++i) acc += V[qkv_idx(b, l0 + i, h, d)];
    red[g][d] = acc;
    float p = 0.f;
    for (int tt = g; tt < tile; tt += 4)
        p += tsum[(bh * NTILES + tt) * DD + d];
    pre2[g][d] = p;
    __syncthreads();

    float off = pre2[0][d] + pre2[1][d] + pre2[2][d] + pre2[3][d];
    for (int gg = 0; gg < g; ++gg) off += red[gg][d];

    // rows l0..l0+31 share one bitmap word: l>>5 == tile*4+g
    unsigned selw = selmap[bh * 128 + (l0 >> 5)];

    float run = off;
    for (int i = 0; i < CH; ++i) {
        run += V[qkv_idx(b, l0 + i, h, d)];
        if (!((selw >> i) & 1u))
            out[qkv_idx(b, l0 + i, h, d)] = run;
    }
}

// ---------------- Fallback-path kernels ----------------------------------------
__global__ __launch_bounds__(256) void k_cumsum_fb(
        const float* __restrict__ V, const float* __restrict__ tsum,
        float* __restrict__ out) {
    int blk = blockIdx.x;
    int tile = blk % NTILES;
    int bh = blk / NTILES;
    int h = bh % HH, b = bh / HH;
    int t = threadIdx.x;
    int d = t & 63, g = t >> 6;
    const int CH = TILE / 4;
    int l0 = tile * TILE + g * CH;

    __shared__ float red[4][DD];
    __shared__ float pre2[4][DD];
    float acc = 0.f;
    for (int i = 0; i < CH; ++i) acc += V[qkv_idx(b, l0 + i, h, d)];
    red[g][d] = acc;
    float p = 0.f;
    for (int tt = g; tt < tile; tt += 4)
        p += tsum[(bh * NTILES + tt) * DD + d];
    pre2[g][d] = p;
    __syncthreads();

    float off = pre2[0][d] + pre2[1][d] + pre2[2][d] + pre2[3][d];
    for (int gg = 0; gg < g; ++gg) off += red[gg][d];

    float run = off;
    for (int i = 0; i < CH; ++i) {
        run += V[qkv_idx(b, l0 + i, h, d)];
        out[qkv_idx(b, l0 + i, h, d)] = run;
    }
}

__global__ __launch_bounds__(256) void k_attn_mono(
        const float* __restrict__ Q, const float* __restrict__ K,
        const float* __restrict__ V, const int* __restrict__ Mtop,
        float* __restrict__ out) {
    int blk = blockIdx.x; // bh*UU + u
    int u = blk % UU;
    int bh = blk / UU;
    int h = bh % HH, b = bh / HH;
    int qi = Mtop[bh * UU + u];
    int t = threadIdx.x;

    __shared__ float scores[LL];
    __shared__ float red[256];

    const float4* qp = (const float4*)(Q + qkv_idx(b, qi, h, 0));
    float4 qreg[16];
#pragma unroll
    for (int i = 0; i < 16; ++i) {
        float4 v = qp[i];
        v.x *= 0.125f; v.y *= 0.125f; v.z *= 0.125f; v.w *= 0.125f;
        qreg[i] = v;
    }

    float lmax = -INFINITY;
    for (int k = t; k < LL; k += 256) {
        const float4* kr = (const float4*)(K + qkv_idx(b, k, h, 0));
        float dot = 0.f;
#pragma unroll
        for (int i = 0; i < 16; ++i) {
            float4 kk = kr[i];
            dot = fmaf(qreg[i].x, kk.x, dot);
            dot = fmaf(qreg[i].y, kk.y, dot);
            dot = fmaf(qreg[i].z, kk.z, dot);
            dot = fmaf(qreg[i].w, kk.w, dot);
        }
        scores[k] = dot;
        lmax = fmaxf(lmax, dot);
    }
    red[t] = lmax;
    __syncthreads();
    for (int off = 128; off >= 1; off >>= 1) {
        if (t < off) red[t] = fmaxf(red[t], red[t + off]);
        __syncthreads();
    }
    float smax = red[0];
    __syncthreads();

    float lsum = 0.f;
    for (int k = t; k < LL; k += 256) {
        float e = __expf(scores[k] - smax);
        scores[k] = e;
        lsum += e;
    }
    red[t] = lsum;
    __syncthreads();
    for (int off = 128; off >= 1; off >>= 1) {
        if (t < off) red[t] += red[t + off];
        __syncthreads();
    }
    float denom = red[0];
    __syncthreads();

    int d = t & 63, g = t >> 6;
    const float4* sc4 = (const float4*)scores;
    float acc = 0.f;
    for (int kb = g; kb < LL / 4; kb += 4) {
        float4 s4 = sc4[kb];
        int kk0 = kb * 4;
        acc = fmaf(s4.x, V[qkv_idx(b, kk0 + 0, h, d)], acc);
        acc = fmaf(s4.y, V[qkv_idx(b, kk0 + 1, h, d)], acc);
        acc = fmaf(s4.z, V[qkv_idx(b, kk0 + 2, h, d)], acc);
        acc = fmaf(s4.w, V[qkv_idx(b, kk0 + 3, h, d)], acc);
    }
    red[t] = acc;
    __syncthreads();
    if (g == 0) {
        float s = red[d] + red[64 + d] + red[128 + d] + red[192 + d];
        out[qkv_idx(b, qi, h, d)] = s / denom;
    }
}

extern "C" void kernel_launch(void* const* d_in, const int* in_sizes, int n_in,
                              void* d_out, int out_size, void* d_ws, size_t ws_size,
                              hipStream_t stream) {
    const float* Q = (const float*)d_in[0];
    const float* K = (const float*)d_in[1];
    const float* V = (const float*)d_in[2];
    const int* idx = (const int*)d_in[3];
    float* out = (float*)d_out;

    float* ws = (float*)d_ws;

    // workspace layout (floats)
    const size_t M_off = 0;                           // 65536
    const size_t tsum_off = 65536;                    // 32768
    const size_t mP_off = 98304;                      // 16*64*45 = 46080
    const size_t lP_off = 144384;                     // 46080
    const size_t top_off = 190464;                    // 720 ints (reserve 1024)
    const size_t sel_off = 191488;                    // 16*128 uints (2048)
    const size_t Op_off = 193536;                     // 16*64*45*64 = 2949120
    const size_t need = (Op_off + (size_t)BB * HH * NC * UU * DD) * 4;

    float* M = ws + M_off;
    float* tsum = ws + tsum_off;

    if (ws_size >= need) {
        float* mPart = ws + mP_off;
        float* lPart = ws + lP_off;
        int* Mtop = (int*)(ws + top_off);
        unsigned* selmap = (unsigned*)(ws + sel_off);
        float* Op = ws + Op_off;

        k_computeM_tilesum<<<NB_CM + NB_TS, 256, 0, stream>>>(Q, K, idx, V,
                                                              M, tsum);
        k_topk<<<BB * HH, 1024, 0, stream>>>(M, Mtop, selmap);
        k_attn_partial<<<BB * HH * NC, 256, 0, stream>>>(Q, K, V, Mtop,
                                                         mPart, lPart, Op);
        k_cumsum_combine<<<NB_CU + NB_CO, 256, 0, stream>>>(
            V, tsum, selmap, Mtop, mPart, lPart, Op, out);
    } else {
        // compact fallback layout
        int* Mtop = (int*)(ws + 65536);
        float* tsum2 = ws + 65536 + 1024;
        k_computeM_tilesum<<<NB_CM + NB_TS, 256, 0, stream>>>(Q, K, idx, V,
                                                              M, tsum2);
        k_topk<<<BB * HH, 1024, 0, stream>>>(M, Mtop, (unsigned*)nullptr);
        k_cumsum_fb<<<BB * HH * NTILES, 256, 0, stream>>>(V, tsum2, out);
        k_attn_mono<<<BB * HH * UU, 256, 0, stream>>>(Q, K, V, Mtop, out);
    }
}